// Round 2
// baseline (580.503 us; speedup 1.0000x reference)
//
#include <hip/hip_runtime.h>
#include <stdint.h>
#include <math.h>

#define NB 16
#define TQ 2048
#define TK 2048
#define DH 128
#define KT (TK / 64)   // 32 k-tiles
#define QB (TQ / 64)   // 32 q-blocks per batch

// padded LDS strides (shorts)
#define QK_STR 136   // 128 + 8
#define VT_STR 72    // 64 + 8
#define P_STR  72

typedef __attribute__((ext_vector_type(8))) short bf16x8;
typedef __attribute__((ext_vector_type(4))) float f32x4;
typedef __attribute__((ext_vector_type(8))) unsigned short u16x8;

__device__ __forceinline__ unsigned short f2b(float f) {
  union { float f; uint32_t u; } v; v.f = f;
  uint32_t u = v.u;
  return (unsigned short)((u + 0x7fffu + ((u >> 16) & 1u)) >> 16);
}

__device__ __forceinline__ u16x8 cvt8(const float* p) {
  const f32x4 a = *(const f32x4*)p;
  const f32x4 b = *(const f32x4*)(p + 4);
  u16x8 o;
#pragma unroll
  for (int j = 0; j < 4; ++j) { o[j] = f2b(a[j]); o[4 + j] = f2b(b[j]); }
  return o;
}

// ---- per-batch counting sort of q-rows by effective length (DESCENDING).
// eff = vl clamped to [0,TK], with vl==0 -> TK (those rows need the full span).
// Descending order guarantees rank q0 of any block holds the block max, so
// attn can read block/wave maxes with a single perm+vlen load.
// Also zeroes the split-K fixup counters (must happen every launch).
__global__ __launch_bounds__(256) void sort_kernel(const int* __restrict__ vlen,
                                                   int* __restrict__ perm,
                                                   int* __restrict__ cnt) {
  __shared__ int cnt_[TK + 1];
  __shared__ int base_[TK + 1];
  __shared__ int psum[256];
  const int b = blockIdx.x;
  const int t = threadIdx.x;

  if (cnt && t < QB) cnt[b * QB + t] = 0;

  int hw = 0;
#pragma unroll
  for (int i = 0; i < 8; ++i) hw |= vlen[2 * i + 1];
  const bool is64 = (hw == 0);

  for (int i = t; i <= TK; i += 256) cnt_[i] = 0;
  __syncthreads();

  int eff[8];
#pragma unroll
  for (int j = 0; j < 8; ++j) {
    const int q = j * 256 + t;
    const int idx = b * TQ + q;
    int v = is64 ? vlen[2 * idx] : vlen[idx];
    v = (v < 0) ? 0 : ((v > TK) ? TK : v);
    eff[j] = (v == 0) ? TK : v;
    atomicAdd(&cnt_[eff[j]], 1);
  }
  __syncthreads();

  // descending prefix: thread t owns positions p = 8t..8t+7, bin e = TK - p
  int loc[8]; int s = 0;
#pragma unroll
  for (int j = 0; j < 8; ++j) { loc[j] = cnt_[TK - (t * 8 + j)]; s += loc[j]; }
  psum[t] = s;
  __syncthreads();
  if (t == 0) {
    int acc = 0;
    for (int i = 0; i < 256; ++i) { const int x = psum[i]; psum[i] = acc; acc += x; }
  }
  __syncthreads();
  int run = psum[t];
#pragma unroll
  for (int j = 0; j < 8; ++j) { base_[TK - (t * 8 + j)] = run; run += loc[j]; }
  __syncthreads();
#pragma unroll
  for (int j = 0; j < 8; ++j) {
    const int rank = atomicAdd(&base_[eff[j]], 1);
    perm[b * TQ + rank] = j * 256 + t;
  }
}

// ---- prep: K f32 -> bf16 row-major; V f32 -> bf16 TILED-transposed:
// Vt[((b*KT + kt)*DH + d)*64 + k]  (16 KB contiguous per k-tile, coalesced writes)
__global__ __launch_bounds__(256) void prep_kernel(const float* __restrict__ K,
                                                   const float* __restrict__ V,
                                                   unsigned short* __restrict__ Kb,
                                                   unsigned short* __restrict__ Vt) {
  __shared__ alignas(16) unsigned short tile[64][136];
  const int t = threadIdx.x;
  const int b = blockIdx.y;
  const int kt = blockIdx.x;
  const int k0 = kt * 64;

  const float* Ks = K + ((size_t)b * TK + k0) * DH;
  unsigned short* Kd = Kb + ((size_t)b * TK + k0) * DH;
#pragma unroll
  for (int i = 0; i < 4; ++i) {
    const int row = i * 16 + (t >> 4);
    const int c0 = (t & 15) * 8;
    *(u16x8*)(Kd + (size_t)row * DH + c0) = cvt8(Ks + (size_t)row * DH + c0);
  }
  const float* Vs = V + ((size_t)b * TK + k0) * DH;
#pragma unroll
  for (int i = 0; i < 4; ++i) {
    const int row = i * 16 + (t >> 4);
    const int c0 = (t & 15) * 8;
    *(u16x8*)(&tile[row][c0]) = cvt8(Vs + (size_t)row * DH + c0);
  }
  __syncthreads();
  {
    const int d = t >> 1;          // 0..127
    const int half = t & 1;        // k-half
    alignas(16) unsigned short tmp[32];
#pragma unroll
    for (int j = 0; j < 32; ++j) tmp[j] = tile[half * 32 + j][d];
    unsigned short* dst = Vt + ((size_t)(b * KT + kt) * DH + d) * 64 + half * 32;
#pragma unroll
    for (int j = 0; j < 4; ++j)
      *(u16x8*)(dst + j * 8) = *(const u16x8*)(&tmp[j * 8]);
  }
}

// ---- fused flash attention, fixed-max softmax (no online rescale).
// p = exp2(s*scale - 32); shift-invariance makes O = (P V)/sum(P) exact, and
// partials across k-chunks are directly addable -> exact split-K.
// Chunked split-K: nch = 1<<nchs chunks of ctiles = KT>>nchs tiles each.
// Block (jq, c) handles tiles [c*ctiles, min(nt, (c+1)*ctiles)). Inactive
// chunks (t0 >= nt) exit after 2 loads (sorted order -> nt from rank q0).
// Last-arriving chunk per q-block combines partials inline (threadfence +
// device-scope atomic counter) and scatters through perm. Blocks whose
// q-block has only one active chunk write out directly (no partial traffic).
__global__ __launch_bounds__(256) void attn_ws(const float* __restrict__ Q,
                                               const unsigned short* __restrict__ Kp,
                                               const unsigned short* __restrict__ Vp,
                                               const int* __restrict__ vlen,
                                               const int* __restrict__ perm,
                                               float* __restrict__ pO,
                                               float* __restrict__ pL,
                                               int* __restrict__ cnt,
                                               float* __restrict__ out,
                                               const int nchs) {
  __shared__ alignas(16) char smem[53248];
  __shared__ int s_bvl[4];
  __shared__ int s_last;
  unsigned short* sQ = (unsigned short*)smem;
  unsigned short* sK = (unsigned short*)(smem + 17408);
  unsigned short* sV = (unsigned short*)(smem + 34816);

  const int tid  = threadIdx.x;
  const int w    = tid >> 6;
  const int lane = tid & 63;
  const int quad = lane >> 4;
  const int l15  = lane & 15;
  const int b    = blockIdx.y;
  const int nch  = 1 << nchs;
  const int ctl  = 5 - nchs;            // log2(ctiles), KT = 32
  const int ctiles = KT >> nchs;
  const int jq     = blockIdx.x >> nchs;
  const int cchunk = blockIdx.x & (nch - 1);
  const int q0 = jq * 64;
  const int qw = q0 + w * 16;

  // valid_lens: detect int32 vs int64 (little-endian: high dwords all zero)
  int hw = 0;
#pragma unroll
  for (int i = 0; i < 8; ++i) hw |= vlen[2 * i + 1];
  const bool is64 = (hw == 0);

  const float kScaleL2 = 0.08838834764831845f * 1.4426950408889634f; // 1/sqrt(128)*log2(e)
  const float kBias    = -32.0f;        // fixed max bound in exp2 domain
  const float kKill    = -1.0e7f;       // exp2 -> exactly 0

  // block/wave max effective length
  int bvl, wvl;
  if (perm) {
    // sorted descending: rank q0 / qw hold the block / wave maxes
    const int qb0 = perm[b * TQ + q0];
    const int qw0 = perm[b * TQ + qw];
    int v0 = is64 ? vlen[2 * (b * TQ + qb0)] : vlen[b * TQ + qb0];
    int vw = is64 ? vlen[2 * (b * TQ + qw0)] : vlen[b * TQ + qw0];
    v0 = (v0 < 0) ? 0 : ((v0 > TK) ? TK : v0);
    vw = (vw < 0) ? 0 : ((vw > TK) ? TK : vw);
    bvl = (v0 == 0) ? TK : v0;
    wvl = (vw == 0) ? TK : vw;
  } else {
    int vlr0[4];
#pragma unroll
    for (int r = 0; r < 4; ++r) {
      const int idx = b * TQ + qw + quad * 4 + r;
      int v = is64 ? vlen[2 * idx] : vlen[idx];
      v = (v < 0) ? 0 : ((v > TK) ? TK : v);
      vlr0[r] = (v == 0) ? TK : v;
    }
    int m = 0;
#pragma unroll
    for (int r = 0; r < 4; ++r) m = max(m, vlr0[r]);
    m = max(m, __shfl_xor(m, 16, 64));
    m = max(m, __shfl_xor(m, 32, 64));
    if (lane == 0) s_bvl[w] = m;
    __syncthreads();
    bvl = max(max(s_bvl[0], s_bvl[1]), max(s_bvl[2], s_bvl[3]));
    wvl = m;
  }

  const int nt = (bvl + 63) >> 6;
  const int t0 = cchunk * ctiles;
  const int t1 = (nt < t0 + ctiles) ? nt : (t0 + ctiles);
  if (t0 >= t1) return;                 // inactive chunk: uniform exit
  const int nact = (nt + ctiles - 1) >> ctl;   // active chunks of this q-block

  // per-row lengths / scales / source rows
  int vlr[4]; float scl[4]; int qidx[4];
#pragma unroll
  for (int r = 0; r < 4; ++r) {
    const int rank = qw + quad * 4 + r;
    const int qrow = perm ? perm[b * TQ + rank] : rank;
    qidx[r] = qrow;
    const int idx = b * TQ + qrow;
    int v = is64 ? vlen[2 * idx] : vlen[idx];
    v = (v < 0) ? 0 : ((v > TK) ? TK : v);
    scl[r] = (v == 0) ? 0.0f : kScaleL2;   // vl==0 -> uniform scores
    vlr[r] = (v == 0) ? TK : v;            // vl==0 -> span all of Tk
  }

  // Q staging (rows gathered through perm; each row is 512B contiguous)
#pragma unroll
  for (int i = 0; i < 4; ++i) {
    const int row = i * 16 + (tid >> 4);
    const int qi = perm ? perm[b * TQ + q0 + row] : (q0 + row);
    const int c0 = (tid & 15) * 8;
    *(u16x8*)(sQ + row * QK_STR + c0) = cvt8(Q + ((size_t)b * TQ + qi) * DH + c0);
  }
  __syncthreads();

  // Q fragments (A-layout: m=l15, k=quad*8+j per K=32 chunk kc)
  bf16x8 qa[4];
  {
    const unsigned short* qrow = sQ + (w * 16 + l15) * QK_STR;
#pragma unroll
    for (int kc = 0; kc < 4; ++kc)
      qa[kc] = *(const bf16x8*)(qrow + (kc * 4 + quad) * 8);
  }
  unsigned short* sP = (unsigned short*)smem + w * (16 * P_STR);  // aliases sQ

  f32x4 Of[8] = {};
  float l_r[4] = {0.f, 0.f, 0.f, 0.f};   // per-lane partial row sums

  const unsigned short* Kbase = Kp + (size_t)b * TK * DH;
  const unsigned short* Vbase = Vp + (size_t)(b * KT) * DH * 64;
  const int krow = tid >> 4;
  const int kch  = tid & 15;

  u16x8 kreg[4], vreg[4];
  // prefetch tile t0
  {
    const unsigned short* Ksrc = Kbase + (size_t)t0 * 64 * DH;
#pragma unroll
    for (int i = 0; i < 4; ++i)
      kreg[i] = *(const u16x8*)(Ksrc + (size_t)(i * 16 + krow) * DH + kch * 8);
    const unsigned short* Vsrc = Vbase + (size_t)t0 * (DH * 64);
#pragma unroll
    for (int i = 0; i < 4; ++i)
      vreg[i] = *(const u16x8*)(Vsrc + (i * 256 + tid) * 8);
  }

  for (int t = t0; t < t1; ++t) {
    // store prefetched tile into LDS
#pragma unroll
    for (int i = 0; i < 4; ++i)
      *(u16x8*)(sK + (i * 16 + krow) * QK_STR + kch * 8) = kreg[i];
#pragma unroll
    for (int i = 0; i < 4; ++i) {
      const int chunk = i * 256 + tid;
      *(u16x8*)(sV + (chunk >> 3) * VT_STR + (chunk & 7) * 8) = vreg[i];
    }
    __syncthreads();

    // issue next tile's global loads early
    if (t + 1 < t1) {
      const unsigned short* Ksrc = Kbase + (size_t)(t + 1) * 64 * DH;
#pragma unroll
      for (int i = 0; i < 4; ++i)
        kreg[i] = *(const u16x8*)(Ksrc + (size_t)(i * 16 + krow) * DH + kch * 8);
      const unsigned short* Vsrc = Vbase + (size_t)(t + 1) * (DH * 64);
#pragma unroll
      for (int i = 0; i < 4; ++i)
        vreg[i] = *(const u16x8*)(Vsrc + (i * 256 + tid) * 8);
    }

    const int k0 = t * 64;
    if (k0 < wvl) {   // wave-uniform skip of fully-masked tiles
      // S = Q K^T  (C: col=l15=kpos, row=quad*4+reg=q-row)
      f32x4 sc[4] = {};
#pragma unroll
      for (int ct = 0; ct < 4; ++ct) {
        const unsigned short* kr = sK + (ct * 16 + l15) * QK_STR;
#pragma unroll
        for (int kc = 0; kc < 4; ++kc) {
          const bf16x8 kf = *(const bf16x8*)(kr + (kc * 4 + quad) * 8);
          sc[ct] = __builtin_amdgcn_mfma_f32_16x16x32_bf16(qa[kc], kf, sc[ct], 0, 0, 0);
        }
      }

      // fixed-max masked softmax numerator, accumulate row sums per-lane
      unsigned short pb[4][4];
#pragma unroll
      for (int ct = 0; ct < 4; ++ct) {
        const int kpos = k0 + ct * 16 + l15;
#pragma unroll
        for (int r = 0; r < 4; ++r) {
          const float s = (kpos < vlr[r]) ? fmaf(sc[ct][r], scl[r], kBias) : kKill;
          const float p = exp2f(s);
          l_r[r] += p;
          pb[ct][r] = f2b(p);
        }
      }

      // P (C-layout) -> per-wave LDS; same-wave DS ops in order
#pragma unroll
      for (int ct = 0; ct < 4; ++ct)
#pragma unroll
        for (int r = 0; r < 4; ++r)
          sP[(quad * 4 + r) * P_STR + ct * 16 + l15] = pb[ct][r];
      __asm__ __volatile__("" ::: "memory");

      bf16x8 pa[2];
      {
        const unsigned short* pr = sP + l15 * P_STR;
#pragma unroll
        for (int ch = 0; ch < 2; ++ch)
          pa[ch] = *(const bf16x8*)(pr + (ch * 4 + quad) * 8);
      }

      // O += P V  (B-frag: n=l15=d-col, k=quad*8+j=kpos)
#pragma unroll
      for (int dt = 0; dt < 8; ++dt) {
        const unsigned short* vr = sV + (dt * 16 + l15) * VT_STR;
#pragma unroll
        for (int ch = 0; ch < 2; ++ch) {
          const bf16x8 vf = *(const bf16x8*)(vr + (ch * 4 + quad) * 8);
          Of[dt] = __builtin_amdgcn_mfma_f32_16x16x32_bf16(pa[ch], vf, Of[dt], 0, 0, 0);
        }
      }
    }
    __syncthreads();
  }

  // one-time cross-lane row-sum reduction (over the 16 l15 lanes per quad)
#pragma unroll
  for (int off = 1; off <= 8; off <<= 1)
#pragma unroll
    for (int r = 0; r < 4; ++r)
      l_r[r] += __shfl_xor(l_r[r], off, 64);

  if (nact == 1) {
    // only chunk 0 active (or unsplit): normalize + scatter directly
#pragma unroll
    for (int r = 0; r < 4; ++r) {
      const float inv = 1.0f / l_r[r];
      float* orow = out + ((size_t)b * TQ + qidx[r]) * DH;
#pragma unroll
      for (int dt = 0; dt < 8; ++dt)
        orow[dt * 16 + l15] = Of[dt][r] * inv;
    }
    return;
  }

  // split path: write partial numerator + denominator (rank-local layout)
  const int qb = b * QB + jq;
  const int slot = qb * nch + cchunk;
  {
    float* po = pO + (size_t)slot * (64 * DH);
    float* pl = pL + (size_t)slot * 64;
#pragma unroll
    for (int r = 0; r < 4; ++r) {
      const int row = w * 16 + quad * 4 + r;
#pragma unroll
      for (int dt = 0; dt < 8; ++dt)
        po[(size_t)row * DH + dt * 16 + l15] = Of[dt][r];
    }
    if (l15 == 0) {
#pragma unroll
      for (int r = 0; r < 4; ++r)
        pl[w * 16 + quad * 4 + r] = l_r[r];
    }
  }

  // fixup: last-arriving chunk combines all partials of this q-block
  __threadfence();            // release our partial writes (device scope)
  __syncthreads();
  if (tid == 0)
    s_last = (atomicAdd(&cnt[qb], 1) == nact - 1) ? 1 : 0;
  __syncthreads();
  if (!s_last) return;

  __threadfence();            // acquire other chunks' partials
  const int qboff = qb * nch;
#pragma unroll
  for (int i = 0; i < 8; ++i) {
    const int u = i * 256 + tid;      // 2048 f32x4 units = 64 rows * 32
    const int r = u >> 5;             // rank-local row
    const int d4 = (u & 31) * 4;
    float lsum = 0.0f;
    f32x4 acc = {0.f, 0.f, 0.f, 0.f};
    for (int c = 0; c < nact; ++c) {
      lsum += pL[(size_t)(qboff + c) * 64 + r];
      acc += *(const f32x4*)(pO + ((size_t)(qboff + c) * 64 + r) * DH + d4);
    }
    const float inv = 1.0f / lsum;
    const int qi = perm[b * TQ + q0 + r];
    *(f32x4*)(out + ((size_t)b * TQ + qi) * DH + d4) = acc * inv;
  }
}

// ---- fallback (no workspace): f32 inputs, in-kernel cvt, strided V B-frags ----
__global__ __launch_bounds__(256) void attn_fb(const float* __restrict__ Q,
                                               const float* __restrict__ Kp,
                                               const float* __restrict__ Vp,
                                               const int* __restrict__ vlen,
                                               float* __restrict__ out) {
  __shared__ alignas(16) char smem[53248];
  __shared__ int s_bvl[4];
  unsigned short* sQ = (unsigned short*)smem;
  unsigned short* sK = (unsigned short*)(smem + 17408);
  unsigned short* sV = (unsigned short*)(smem + 34816);

  const int tid  = threadIdx.x;
  const int w    = tid >> 6;
  const int lane = tid & 63;
  const int quad = lane >> 4;
  const int l15  = lane & 15;
  const int b    = blockIdx.y;
  const int q0   = blockIdx.x * 64;

  const float* Qb = Q + ((size_t)b * TQ + q0) * DH;
#pragma unroll
  for (int i = 0; i < 4; ++i) {
    const int row = i * 16 + (tid >> 4);
    const int c0 = (tid & 15) * 8;
    *(u16x8*)(sQ + row * QK_STR + c0) = cvt8(Qb + (size_t)row * DH + c0);
  }

  int hw = 0;
#pragma unroll
  for (int i = 0; i < 8; ++i) hw |= vlen[2 * i + 1];
  const bool is64 = (hw == 0);

  const float kScaleL2 = 0.08838834764831845f * 1.4426950408889634f;
  const float kBias    = -32.0f;
  const float kKill    = -1.0e7f;

  const int qw = q0 + w * 16;
  int vlr[4];
  float scl[4];
#pragma unroll
  for (int r = 0; r < 4; ++r) {
    const int idx = b * TQ + qw + quad * 4 + r;
    int v = is64 ? vlen[2 * idx] : vlen[idx];
    v = (v < 0) ? 0 : ((v > TK) ? TK : v);
    scl[r] = (v == 0) ? 0.0f : kScaleL2;
    vlr[r] = (v == 0) ? TK : v;
  }
  int wvl = 0;
#pragma unroll
  for (int r = 0; r < 4; ++r) wvl = max(wvl, vlr[r]);
  wvl = max(wvl, __shfl_xor(wvl, 16, 64));
  wvl = max(wvl, __shfl_xor(wvl, 32, 64));
  if (lane == 0) s_bvl[w] = wvl;
  __syncthreads();
  const int bvl = max(max(s_bvl[0], s_bvl[1]), max(s_bvl[2], s_bvl[3]));
  const int nt = (bvl + 63) >> 6;

  bf16x8 qa[4];
  {
    const unsigned short* qrow = sQ + (w * 16 + l15) * QK_STR;
#pragma unroll
    for (int kc = 0; kc < 4; ++kc)
      qa[kc] = *(const bf16x8*)(qrow + (kc * 4 + quad) * 8);
  }
  unsigned short* sP = (unsigned short*)smem + w * (16 * P_STR);

  f32x4 Of[8] = {};
  float l_r[4] = {0.f, 0.f, 0.f, 0.f};

  const float* Kb = Kp + (size_t)b * TK * DH;
  const float* Vb = Vp + (size_t)b * TK * DH;

  for (int t = 0; t < nt; ++t) {
    const int k0 = t * 64;
    __syncthreads();
#pragma unroll
    for (int i = 0; i < 4; ++i) {
      const int row = i * 16 + (tid >> 4);
      const int c0 = (tid & 15) * 8;
      *(u16x8*)(sK + row * QK_STR + c0) = cvt8(Kb + (size_t)(k0 + row) * DH + c0);
    }
#pragma unroll
    for (int i = 0; i < 4; ++i) {
      const int row = i * 16 + (tid >> 4);
      const int c0 = (tid & 15) * 8;
      *(u16x8*)(sV + row * QK_STR + c0) = cvt8(Vb + (size_t)(k0 + row) * DH + c0);
    }
    __syncthreads();
    if (k0 >= wvl) continue;

    f32x4 sc[4] = {};
#pragma unroll
    for (int ct = 0; ct < 4; ++ct) {
      const unsigned short* kr = sK + (ct * 16 + l15) * QK_STR;
#pragma unroll
      for (int kc = 0; kc < 4; ++kc) {
        const bf16x8 kf = *(const bf16x8*)(kr + (kc * 4 + quad) * 8);
        sc[ct] = __builtin_amdgcn_mfma_f32_16x16x32_bf16(qa[kc], kf, sc[ct], 0, 0, 0);
      }
    }
    unsigned short pb[4][4];
#pragma unroll
    for (int ct = 0; ct < 4; ++ct) {
      const int kpos = k0 + ct * 16 + l15;
#pragma unroll
      for (int r = 0; r < 4; ++r) {
        const float s = (kpos < vlr[r]) ? fmaf(sc[ct][r], scl[r], kBias) : kKill;
        const float p = exp2f(s);
        l_r[r] += p;
        pb[ct][r] = f2b(p);
      }
    }
#pragma unroll
    for (int ct = 0; ct < 4; ++ct)
#pragma unroll
      for (int r = 0; r < 4; ++r)
        sP[(quad * 4 + r) * P_STR + ct * 16 + l15] = pb[ct][r];
    __asm__ __volatile__("" ::: "memory");
    bf16x8 pa[2];
    {
      const unsigned short* pr = sP + l15 * P_STR;
#pragma unroll
      for (int ch = 0; ch < 2; ++ch)
        pa[ch] = *(const bf16x8*)(pr + (ch * 4 + quad) * 8);
    }
#pragma unroll
    for (int dt = 0; dt < 8; ++dt) {
      const int col = dt * 16 + l15;
#pragma unroll
      for (int ch = 0; ch < 2; ++ch) {
        bf16x8 vf;
#pragma unroll
        for (int j = 0; j < 8; ++j) {
          const int k = ch * 32 + quad * 8 + j;
          vf[j] = ((const short*)sV)[k * QK_STR + col];
        }
        Of[dt] = __builtin_amdgcn_mfma_f32_16x16x32_bf16(pa[ch], vf, Of[dt], 0, 0, 0);
      }
    }
  }

#pragma unroll
  for (int off = 1; off <= 8; off <<= 1)
#pragma unroll
    for (int r = 0; r < 4; ++r)
      l_r[r] += __shfl_xor(l_r[r], off, 64);

#pragma unroll
  for (int r = 0; r < 4; ++r) {
    const float inv = 1.0f / l_r[r];
    const int q = qw + quad * 4 + r;
    float* orow = out + ((size_t)b * TQ + q) * DH;
#pragma unroll
    for (int dt = 0; dt < 8; ++dt)
      orow[dt * 16 + l15] = Of[dt][r] * inv;
  }
}

extern "C" void kernel_launch(void* const* d_in, const int* in_sizes, int n_in,
                              void* d_out, int out_size, void* d_ws, size_t ws_size,
                              hipStream_t stream) {
  const float* Q = (const float*)d_in[0];
  const float* K = (const float*)d_in[1];
  const float* V = (const float*)d_in[2];
  const int* vl  = (const int*)d_in[3];
  float* out     = (float*)d_out;

  const size_t kb    = (size_t)NB * TK * DH;            // elements per tensor
  const size_t kvB   = kb * 2 * 2;                      // Kb + Vt (bf16, 16.8 MB)
  const size_t permB = (size_t)NB * TQ * sizeof(int);   // 131 KB
  const size_t cntB  = 4096;                            // NB*QB ints, padded
  const size_t baseB = kvB + permB + cntB;

  // pick deepest split the workspace allows: nchs=2 (4 chunks of 8 tiles),
  // nchs=1 (2 chunks of 16), nchs=0 (unsplit)
  int nchs = -1;
  size_t pLB = 0, pOB = 0;
  for (int s = 2; s >= 0; --s) {
    const size_t nch = (size_t)1 << s;
    const size_t plb = (size_t)NB * QB * nch * 64 * sizeof(float);
    const size_t pob = (size_t)NB * QB * nch * 64 * DH * sizeof(float);
    const size_t need = (s > 0) ? (baseB + plb + pob) : (kvB + permB);
    if (ws_size >= need) { nchs = s; pLB = plb; pOB = pob; break; }
  }

  if (nchs >= 0) {
    unsigned short* Kb = (unsigned short*)d_ws;
    unsigned short* Vt = Kb + kb;
    int*   perm = (int*)((char*)d_ws + kvB);
    int*   cnt  = (nchs > 0) ? (int*)((char*)d_ws + kvB + permB) : nullptr;
    float* pL   = (nchs > 0) ? (float*)((char*)d_ws + baseB) : nullptr;
    float* pO   = (nchs > 0) ? (float*)((char*)d_ws + baseB + pLB) : nullptr;
    sort_kernel<<<dim3(NB), 256, 0, stream>>>(vl, perm, cnt);
    prep_kernel<<<dim3(KT, NB), 256, 0, stream>>>(K, V, Kb, Vt);
    attn_ws<<<dim3(QB << nchs, NB), 256, 0, stream>>>(Q, Kb, Vt, vl, perm,
                                                      pO, pL, cnt, out, nchs);
  } else if (ws_size >= kvB) {
    // unsorted unsplit (previous behavior)
    unsigned short* Kb = (unsigned short*)d_ws;
    unsigned short* Vt = Kb + kb;
    prep_kernel<<<dim3(KT, NB), 256, 0, stream>>>(K, V, Kb, Vt);
    attn_ws<<<dim3(QB, NB), 256, 0, stream>>>(Q, Kb, Vt, vl, nullptr,
                                              nullptr, nullptr, nullptr, out, 0);
  } else {
    attn_fb<<<dim3(QB, NB), 256, 0, stream>>>(Q, K, V, vl, out);
  }
}

// Round 3
// 207.484 us; speedup vs baseline: 2.7978x; 2.7978x over previous
//
#include <hip/hip_runtime.h>
#include <stdint.h>
#include <math.h>

#define NB 16
#define TQ 2048
#define TK 2048
#define DH 128
#define KT (TK / 64)   // 32 k-tiles
#define QB (TQ / 64)   // 32 q-blocks per batch

// padded LDS strides (shorts)
#define QK_STR 136   // 128 + 8
#define VT_STR 72    // 64 + 8
#define P_STR  72

typedef __attribute__((ext_vector_type(8))) short bf16x8;
typedef __attribute__((ext_vector_type(4))) float f32x4;
typedef __attribute__((ext_vector_type(8))) unsigned short u16x8;

__device__ __forceinline__ unsigned short f2b(float f) {
  union { float f; uint32_t u; } v; v.f = f;
  uint32_t u = v.u;
  return (unsigned short)((u + 0x7fffu + ((u >> 16) & 1u)) >> 16);
}

__device__ __forceinline__ u16x8 cvt8(const float* p) {
  const f32x4 a = *(const f32x4*)p;
  const f32x4 b = *(const f32x4*)(p + 4);
  u16x8 o;
#pragma unroll
  for (int j = 0; j < 4; ++j) { o[j] = f2b(a[j]); o[4 + j] = f2b(b[j]); }
  return o;
}

// effective length: clamp to [0,TK]; vl==0 spans all of TK (uniform softmax)
__device__ __forceinline__ int eff_len(const int* vlen, bool is64, int idx) {
  int v = is64 ? vlen[2 * idx] : vlen[idx];
  v = (v < 0) ? 0 : ((v > TK) ? TK : v);
  return (v == 0) ? TK : v;
}

// ---- per-batch counting sort of q-rows by effective length (DESCENDING).
// Descending order guarantees rank q0 of any block holds the block max, so
// consumers read block/wave maxes with a single perm+vlen load.
__global__ __launch_bounds__(256) void sort_kernel(const int* __restrict__ vlen,
                                                   int* __restrict__ perm) {
  __shared__ int cnt_[TK + 1];
  __shared__ int base_[TK + 1];
  __shared__ int psum[256];
  const int b = blockIdx.x;
  const int t = threadIdx.x;

  int hw = 0;
#pragma unroll
  for (int i = 0; i < 8; ++i) hw |= vlen[2 * i + 1];
  const bool is64 = (hw == 0);

  for (int i = t; i <= TK; i += 256) cnt_[i] = 0;
  __syncthreads();

  int eff[8];
#pragma unroll
  for (int j = 0; j < 8; ++j) {
    const int q = j * 256 + t;
    eff[j] = eff_len(vlen, is64, b * TQ + q);
    atomicAdd(&cnt_[eff[j]], 1);
  }
  __syncthreads();

  // descending prefix: thread t owns positions p = 8t..8t+7, bin e = TK - p
  int loc[8]; int s = 0;
#pragma unroll
  for (int j = 0; j < 8; ++j) { loc[j] = cnt_[TK - (t * 8 + j)]; s += loc[j]; }
  psum[t] = s;
  __syncthreads();
  if (t == 0) {
    int acc = 0;
    for (int i = 0; i < 256; ++i) { const int x = psum[i]; psum[i] = acc; acc += x; }
  }
  __syncthreads();
  int run = psum[t];
#pragma unroll
  for (int j = 0; j < 8; ++j) { base_[TK - (t * 8 + j)] = run; run += loc[j]; }
  __syncthreads();
#pragma unroll
  for (int j = 0; j < 8; ++j) {
    const int rank = atomicAdd(&base_[eff[j]], 1);
    perm[b * TQ + rank] = j * 256 + t;
  }
}

// ---- prep: K f32 -> bf16 row-major; V f32 -> bf16 TILED-transposed:
// Vt[((b*KT + kt)*DH + d)*64 + k]  (16 KB contiguous per k-tile, coalesced writes)
__global__ __launch_bounds__(256) void prep_kernel(const float* __restrict__ K,
                                                   const float* __restrict__ V,
                                                   unsigned short* __restrict__ Kb,
                                                   unsigned short* __restrict__ Vt) {
  __shared__ alignas(16) unsigned short tile[64][136];
  const int t = threadIdx.x;
  const int b = blockIdx.y;
  const int kt = blockIdx.x;
  const int k0 = kt * 64;

  const float* Ks = K + ((size_t)b * TK + k0) * DH;
  unsigned short* Kd = Kb + ((size_t)b * TK + k0) * DH;
#pragma unroll
  for (int i = 0; i < 4; ++i) {
    const int row = i * 16 + (t >> 4);
    const int c0 = (t & 15) * 8;
    *(u16x8*)(Kd + (size_t)row * DH + c0) = cvt8(Ks + (size_t)row * DH + c0);
  }
  const float* Vs = V + ((size_t)b * TK + k0) * DH;
#pragma unroll
  for (int i = 0; i < 4; ++i) {
    const int row = i * 16 + (t >> 4);
    const int c0 = (t & 15) * 8;
    *(u16x8*)(&tile[row][c0]) = cvt8(Vs + (size_t)row * DH + c0);
  }
  __syncthreads();
  {
    const int d = t >> 1;          // 0..127
    const int half = t & 1;        // k-half
    alignas(16) unsigned short tmp[32];
#pragma unroll
    for (int j = 0; j < 32; ++j) tmp[j] = tile[half * 32 + j][d];
    unsigned short* dst = Vt + ((size_t)(b * KT + kt) * DH + d) * 64 + half * 32;
#pragma unroll
    for (int j = 0; j < 4; ++j)
      *(u16x8*)(dst + j * 8) = *(const u16x8*)(&tmp[j * 8]);
  }
}

// ---- fused flash attention, fixed-max softmax (no online rescale).
// p = exp2(s*scale - 32); shift-invariance makes O = (P V)/sum(P) exact, and
// partials across k-chunks are directly addable -> exact split-K.
// Chunked split-K: nch = 1<<nchs chunks of ctiles = KT>>nchs tiles each.
// Block (jq, c) handles tiles [c*ctiles, min(nt, (c+1)*ctiles)). Inactive
// chunks (t0 >= nt) exit after 2 loads (sorted order -> nt from rank q0).
// q-blocks with a single active chunk normalize + scatter directly; others
// write partial (O_num, l) and a SEPARATE combine kernel finishes them.
// NOTE: no per-block __threadfence here. Round-2 post-mortem: device-scope
// fences compile to per-XCD L2 writeback/invalidate (buffer_wbl2/inv) and
// ~2000 of them stretched this kernel 5.6x. The kernel boundary before
// combine_kernel provides the cross-XCD visibility for free.
__global__ __launch_bounds__(256) void attn_ws(const float* __restrict__ Q,
                                               const unsigned short* __restrict__ Kp,
                                               const unsigned short* __restrict__ Vp,
                                               const int* __restrict__ vlen,
                                               const int* __restrict__ perm,
                                               float* __restrict__ pO,
                                               float* __restrict__ pL,
                                               float* __restrict__ out,
                                               const int nchs) {
  __shared__ alignas(16) char smem[53248];
  __shared__ int s_bvl[4];
  unsigned short* sQ = (unsigned short*)smem;
  unsigned short* sK = (unsigned short*)(smem + 17408);
  unsigned short* sV = (unsigned short*)(smem + 34816);

  const int tid  = threadIdx.x;
  const int w    = tid >> 6;
  const int lane = tid & 63;
  const int quad = lane >> 4;
  const int l15  = lane & 15;
  const int b    = blockIdx.y;
  const int nch  = 1 << nchs;
  const int ctl  = 5 - nchs;            // log2(ctiles), KT = 32
  const int ctiles = KT >> nchs;
  const int jq     = blockIdx.x >> nchs;
  const int cchunk = blockIdx.x & (nch - 1);
  const int q0 = jq * 64;
  const int qw = q0 + w * 16;

  // valid_lens: detect int32 vs int64 (little-endian: high dwords all zero)
  int hw = 0;
#pragma unroll
  for (int i = 0; i < 8; ++i) hw |= vlen[2 * i + 1];
  const bool is64 = (hw == 0);

  const float kScaleL2 = 0.08838834764831845f * 1.4426950408889634f; // 1/sqrt(128)*log2(e)
  const float kBias    = -32.0f;        // fixed max bound in exp2 domain
  const float kKill    = -1.0e7f;       // exp2 -> exactly 0

  // block/wave max effective length
  int bvl, wvl;
  if (perm) {
    // sorted descending: rank q0 / qw hold the block / wave maxes
    bvl = eff_len(vlen, is64, b * TQ + perm[b * TQ + q0]);
    wvl = eff_len(vlen, is64, b * TQ + perm[b * TQ + qw]);
  } else {
    int m = 0;
#pragma unroll
    for (int r = 0; r < 4; ++r)
      m = max(m, eff_len(vlen, is64, b * TQ + qw + quad * 4 + r));
    m = max(m, __shfl_xor(m, 16, 64));
    m = max(m, __shfl_xor(m, 32, 64));
    if (lane == 0) s_bvl[w] = m;
    __syncthreads();
    bvl = max(max(s_bvl[0], s_bvl[1]), max(s_bvl[2], s_bvl[3]));
    wvl = m;
  }

  const int nt = (bvl + 63) >> 6;
  const int t0 = cchunk * ctiles;
  const int t1 = (nt < t0 + ctiles) ? nt : (t0 + ctiles);
  if (t0 >= t1) return;                 // inactive chunk: uniform exit
  const int nact = (nt + ctiles - 1) >> ctl;   // active chunks of this q-block

  // per-row lengths / scales / source rows
  int vlr[4]; float scl[4]; int qidx[4];
#pragma unroll
  for (int r = 0; r < 4; ++r) {
    const int rank = qw + quad * 4 + r;
    const int qrow = perm ? perm[b * TQ + rank] : rank;
    qidx[r] = qrow;
    const int idx = b * TQ + qrow;
    int v = is64 ? vlen[2 * idx] : vlen[idx];
    v = (v < 0) ? 0 : ((v > TK) ? TK : v);
    scl[r] = (v == 0) ? 0.0f : kScaleL2;   // vl==0 -> uniform scores
    vlr[r] = (v == 0) ? TK : v;            // vl==0 -> span all of Tk
  }

  // Q staging (rows gathered through perm; each row is 512B contiguous)
#pragma unroll
  for (int i = 0; i < 4; ++i) {
    const int row = i * 16 + (tid >> 4);
    const int qi = perm ? perm[b * TQ + q0 + row] : (q0 + row);
    const int c0 = (tid & 15) * 8;
    *(u16x8*)(sQ + row * QK_STR + c0) = cvt8(Q + ((size_t)b * TQ + qi) * DH + c0);
  }
  __syncthreads();

  // Q fragments (A-layout: m=l15, k=quad*8+j per K=32 chunk kc)
  bf16x8 qa[4];
  {
    const unsigned short* qrow = sQ + (w * 16 + l15) * QK_STR;
#pragma unroll
    for (int kc = 0; kc < 4; ++kc)
      qa[kc] = *(const bf16x8*)(qrow + (kc * 4 + quad) * 8);
  }
  unsigned short* sP = (unsigned short*)smem + w * (16 * P_STR);  // aliases sQ

  f32x4 Of[8] = {};
  float l_r[4] = {0.f, 0.f, 0.f, 0.f};   // per-lane partial row sums

  const unsigned short* Kbase = Kp + (size_t)b * TK * DH;
  const unsigned short* Vbase = Vp + (size_t)(b * KT) * DH * 64;
  const int krow = tid >> 4;
  const int kch  = tid & 15;

  u16x8 kreg[4], vreg[4];
  // prefetch tile t0
  {
    const unsigned short* Ksrc = Kbase + (size_t)t0 * 64 * DH;
#pragma unroll
    for (int i = 0; i < 4; ++i)
      kreg[i] = *(const u16x8*)(Ksrc + (size_t)(i * 16 + krow) * DH + kch * 8);
    const unsigned short* Vsrc = Vbase + (size_t)t0 * (DH * 64);
#pragma unroll
    for (int i = 0; i < 4; ++i)
      vreg[i] = *(const u16x8*)(Vsrc + (i * 256 + tid) * 8);
  }

  for (int t = t0; t < t1; ++t) {
    // store prefetched tile into LDS
#pragma unroll
    for (int i = 0; i < 4; ++i)
      *(u16x8*)(sK + (i * 16 + krow) * QK_STR + kch * 8) = kreg[i];
#pragma unroll
    for (int i = 0; i < 4; ++i) {
      const int chunk = i * 256 + tid;
      *(u16x8*)(sV + (chunk >> 3) * VT_STR + (chunk & 7) * 8) = vreg[i];
    }
    __syncthreads();

    // issue next tile's global loads early
    if (t + 1 < t1) {
      const unsigned short* Ksrc = Kbase + (size_t)(t + 1) * 64 * DH;
#pragma unroll
      for (int i = 0; i < 4; ++i)
        kreg[i] = *(const u16x8*)(Ksrc + (size_t)(i * 16 + krow) * DH + kch * 8);
      const unsigned short* Vsrc = Vbase + (size_t)(t + 1) * (DH * 64);
#pragma unroll
      for (int i = 0; i < 4; ++i)
        vreg[i] = *(const u16x8*)(Vsrc + (i * 256 + tid) * 8);
    }

    const int k0 = t * 64;
    if (k0 < wvl) {   // wave-uniform skip of fully-masked tiles
      // S = Q K^T  (C: col=l15=kpos, row=quad*4+reg=q-row)
      f32x4 sc[4] = {};
#pragma unroll
      for (int ct = 0; ct < 4; ++ct) {
        const unsigned short* kr = sK + (ct * 16 + l15) * QK_STR;
#pragma unroll
        for (int kc = 0; kc < 4; ++kc) {
          const bf16x8 kf = *(const bf16x8*)(kr + (kc * 4 + quad) * 8);
          sc[ct] = __builtin_amdgcn_mfma_f32_16x16x32_bf16(qa[kc], kf, sc[ct], 0, 0, 0);
        }
      }

      // fixed-max masked softmax numerator, accumulate row sums per-lane
      unsigned short pb[4][4];
#pragma unroll
      for (int ct = 0; ct < 4; ++ct) {
        const int kpos = k0 + ct * 16 + l15;
#pragma unroll
        for (int r = 0; r < 4; ++r) {
          const float s = (kpos < vlr[r]) ? fmaf(sc[ct][r], scl[r], kBias) : kKill;
          const float p = exp2f(s);
          l_r[r] += p;
          pb[ct][r] = f2b(p);
        }
      }

      // P (C-layout) -> per-wave LDS; same-wave DS ops in order
#pragma unroll
      for (int ct = 0; ct < 4; ++ct)
#pragma unroll
        for (int r = 0; r < 4; ++r)
          sP[(quad * 4 + r) * P_STR + ct * 16 + l15] = pb[ct][r];
      __asm__ __volatile__("" ::: "memory");

      bf16x8 pa[2];
      {
        const unsigned short* pr = sP + l15 * P_STR;
#pragma unroll
        for (int ch = 0; ch < 2; ++ch)
          pa[ch] = *(const bf16x8*)(pr + (ch * 4 + quad) * 8);
      }

      // O += P V  (B-frag: n=l15=d-col, k=quad*8+j=kpos)
#pragma unroll
      for (int dt = 0; dt < 8; ++dt) {
        const unsigned short* vr = sV + (dt * 16 + l15) * VT_STR;
#pragma unroll
        for (int ch = 0; ch < 2; ++ch) {
          const bf16x8 vf = *(const bf16x8*)(vr + (ch * 4 + quad) * 8);
          Of[dt] = __builtin_amdgcn_mfma_f32_16x16x32_bf16(pa[ch], vf, Of[dt], 0, 0, 0);
        }
      }
    }
    __syncthreads();
  }

  // one-time cross-lane row-sum reduction (over the 16 l15 lanes per quad)
#pragma unroll
  for (int off = 1; off <= 8; off <<= 1)
#pragma unroll
    for (int r = 0; r < 4; ++r)
      l_r[r] += __shfl_xor(l_r[r], off, 64);

  if (nact == 1) {
    // only chunk 0 active (or unsplit): normalize + scatter directly
#pragma unroll
    for (int r = 0; r < 4; ++r) {
      const float inv = 1.0f / l_r[r];
      float* orow = out + ((size_t)b * TQ + qidx[r]) * DH;
#pragma unroll
      for (int dt = 0; dt < 8; ++dt)
        orow[dt * 16 + l15] = Of[dt][r] * inv;
    }
    return;
  }

  // split path: write partial numerator + denominator (rank-local layout);
  // combine_kernel (next launch) finishes. Kernel boundary = coherence.
  const int slot = (b * QB + jq) * nch + cchunk;
  float* po = pO + (size_t)slot * (64 * DH);
  float* pl = pL + (size_t)slot * 64;
#pragma unroll
  for (int r = 0; r < 4; ++r) {
    const int row = w * 16 + quad * 4 + r;
#pragma unroll
    for (int dt = 0; dt < 8; ++dt)
      po[(size_t)row * DH + dt * 16 + l15] = Of[dt][r];
  }
  if (l15 == 0) {
#pragma unroll
    for (int r = 0; r < 4; ++r)
      pl[w * 16 + quad * 4 + r] = l_r[r];
  }
}

// ---- combine: O = (Σ_c P_c) / (Σ_c l_c), scatter rank -> q via perm.
// Only q-blocks with nact >= 2 have pending partials; others exit fast.
__global__ __launch_bounds__(256) void combine_kernel(const float* __restrict__ pO,
                                                      const float* __restrict__ pL,
                                                      const int* __restrict__ perm,
                                                      const int* __restrict__ vlen,
                                                      float* __restrict__ out,
                                                      const int nchs) {
  const int b = blockIdx.y;
  const int j = blockIdx.x;
  const int t = threadIdx.x;
  const int nch = 1 << nchs;
  const int ctl = 5 - nchs;

  int hw = 0;
#pragma unroll
  for (int i = 0; i < 8; ++i) hw |= vlen[2 * i + 1];
  const bool is64 = (hw == 0);

  const int bvl = eff_len(vlen, is64, b * TQ + perm[b * TQ + j * 64]);
  const int nt = (bvl + 63) >> 6;
  const int nact = (nt + (1 << ctl) - 1) >> ctl;
  if (nact <= 1) return;   // handled by attn_ws direct path

  const int qboff = (b * QB + j) * nch;
#pragma unroll
  for (int i = 0; i < 8; ++i) {
    const int u = i * 256 + t;        // 2048 f32x4 units = 64 rows * 32
    const int r = u >> 5;             // rank-local row
    const int d4 = (u & 31) * 4;
    float lsum = 0.0f;
    f32x4 acc = {0.f, 0.f, 0.f, 0.f};
    for (int c = 0; c < nact; ++c) {
      lsum += pL[(size_t)(qboff + c) * 64 + r];
      acc += *(const f32x4*)(pO + ((size_t)(qboff + c) * 64 + r) * DH + d4);
    }
    const float inv = 1.0f / lsum;
    const int qi = perm[b * TQ + j * 64 + r];
    *(f32x4*)(out + ((size_t)b * TQ + qi) * DH + d4) = acc * inv;
  }
}

// ---- fallback (no workspace): f32 inputs, in-kernel cvt, strided V B-frags ----
__global__ __launch_bounds__(256) void attn_fb(const float* __restrict__ Q,
                                               const float* __restrict__ Kp,
                                               const float* __restrict__ Vp,
                                               const int* __restrict__ vlen,
                                               float* __restrict__ out) {
  __shared__ alignas(16) char smem[53248];
  __shared__ int s_bvl[4];
  unsigned short* sQ = (unsigned short*)smem;
  unsigned short* sK = (unsigned short*)(smem + 17408);
  unsigned short* sV = (unsigned short*)(smem + 34816);

  const int tid  = threadIdx.x;
  const int w    = tid >> 6;
  const int lane = tid & 63;
  const int quad = lane >> 4;
  const int l15  = lane & 15;
  const int b    = blockIdx.y;
  const int q0   = blockIdx.x * 64;

  const float* Qb = Q + ((size_t)b * TQ + q0) * DH;
#pragma unroll
  for (int i = 0; i < 4; ++i) {
    const int row = i * 16 + (tid >> 4);
    const int c0 = (tid & 15) * 8;
    *(u16x8*)(sQ + row * QK_STR + c0) = cvt8(Qb + (size_t)row * DH + c0);
  }

  int hw = 0;
#pragma unroll
  for (int i = 0; i < 8; ++i) hw |= vlen[2 * i + 1];
  const bool is64 = (hw == 0);

  const float kScaleL2 = 0.08838834764831845f * 1.4426950408889634f;
  const float kBias    = -32.0f;
  const float kKill    = -1.0e7f;

  const int qw = q0 + w * 16;
  int vlr[4];
  float scl[4];
#pragma unroll
  for (int r = 0; r < 4; ++r) {
    const int idx = b * TQ + qw + quad * 4 + r;
    int v = is64 ? vlen[2 * idx] : vlen[idx];
    v = (v < 0) ? 0 : ((v > TK) ? TK : v);
    scl[r] = (v == 0) ? 0.0f : kScaleL2;
    vlr[r] = (v == 0) ? TK : v;
  }
  int wvl = 0;
#pragma unroll
  for (int r = 0; r < 4; ++r) wvl = max(wvl, vlr[r]);
  wvl = max(wvl, __shfl_xor(wvl, 16, 64));
  wvl = max(wvl, __shfl_xor(wvl, 32, 64));
  if (lane == 0) s_bvl[w] = wvl;
  __syncthreads();
  const int bvl = max(max(s_bvl[0], s_bvl[1]), max(s_bvl[2], s_bvl[3]));
  const int nt = (bvl + 63) >> 6;

  bf16x8 qa[4];
  {
    const unsigned short* qrow = sQ + (w * 16 + l15) * QK_STR;
#pragma unroll
    for (int kc = 0; kc < 4; ++kc)
      qa[kc] = *(const bf16x8*)(qrow + (kc * 4 + quad) * 8);
  }
  unsigned short* sP = (unsigned short*)smem + w * (16 * P_STR);

  f32x4 Of[8] = {};
  float l_r[4] = {0.f, 0.f, 0.f, 0.f};

  const float* Kb = Kp + (size_t)b * TK * DH;
  const float* Vb = Vp + (size_t)b * TK * DH;

  for (int t = 0; t < nt; ++t) {
    const int k0 = t * 64;
    __syncthreads();
#pragma unroll
    for (int i = 0; i < 4; ++i) {
      const int row = i * 16 + (tid >> 4);
      const int c0 = (tid & 15) * 8;
      *(u16x8*)(sK + row * QK_STR + c0) = cvt8(Kb + (size_t)(k0 + row) * DH + c0);
    }
#pragma unroll
    for (int i = 0; i < 4; ++i) {
      const int row = i * 16 + (tid >> 4);
      const int c0 = (tid & 15) * 8;
      *(u16x8*)(sV + row * QK_STR + c0) = cvt8(Vb + (size_t)(k0 + row) * DH + c0);
    }
    __syncthreads();
    if (k0 >= wvl) continue;

    f32x4 sc[4] = {};
#pragma unroll
    for (int ct = 0; ct < 4; ++ct) {
      const unsigned short* kr = sK + (ct * 16 + l15) * QK_STR;
#pragma unroll
      for (int kc = 0; kc < 4; ++kc) {
        const bf16x8 kf = *(const bf16x8*)(kr + (kc * 4 + quad) * 8);
        sc[ct] = __builtin_amdgcn_mfma_f32_16x16x32_bf16(qa[kc], kf, sc[ct], 0, 0, 0);
      }
    }
    unsigned short pb[4][4];
#pragma unroll
    for (int ct = 0; ct < 4; ++ct) {
      const int kpos = k0 + ct * 16 + l15;
#pragma unroll
      for (int r = 0; r < 4; ++r) {
        const float s = (kpos < vlr[r]) ? fmaf(sc[ct][r], scl[r], kBias) : kKill;
        const float p = exp2f(s);
        l_r[r] += p;
        pb[ct][r] = f2b(p);
      }
    }
#pragma unroll
    for (int ct = 0; ct < 4; ++ct)
#pragma unroll
      for (int r = 0; r < 4; ++r)
        sP[(quad * 4 + r) * P_STR + ct * 16 + l15] = pb[ct][r];
    __asm__ __volatile__("" ::: "memory");
    bf16x8 pa[2];
    {
      const unsigned short* pr = sP + l15 * P_STR;
#pragma unroll
      for (int ch = 0; ch < 2; ++ch)
        pa[ch] = *(const bf16x8*)(pr + (ch * 4 + quad) * 8);
    }
#pragma unroll
    for (int dt = 0; dt < 8; ++dt) {
      const int col = dt * 16 + l15;
#pragma unroll
      for (int ch = 0; ch < 2; ++ch) {
        bf16x8 vf;
#pragma unroll
        for (int j = 0; j < 8; ++j) {
          const int k = ch * 32 + quad * 8 + j;
          vf[j] = ((const short*)sV)[k * QK_STR + col];
        }
        Of[dt] = __builtin_amdgcn_mfma_f32_16x16x32_bf16(pa[ch], vf, Of[dt], 0, 0, 0);
      }
    }
  }

#pragma unroll
  for (int off = 1; off <= 8; off <<= 1)
#pragma unroll
    for (int r = 0; r < 4; ++r)
      l_r[r] += __shfl_xor(l_r[r], off, 64);

#pragma unroll
  for (int r = 0; r < 4; ++r) {
    const float inv = 1.0f / l_r[r];
    const int q = qw + quad * 4 + r;
    float* orow = out + ((size_t)b * TQ + q) * DH;
#pragma unroll
    for (int dt = 0; dt < 8; ++dt)
      orow[dt * 16 + l15] = Of[dt][r] * inv;
  }
}

extern "C" void kernel_launch(void* const* d_in, const int* in_sizes, int n_in,
                              void* d_out, int out_size, void* d_ws, size_t ws_size,
                              hipStream_t stream) {
  const float* Q = (const float*)d_in[0];
  const float* K = (const float*)d_in[1];
  const float* V = (const float*)d_in[2];
  const int* vl  = (const int*)d_in[3];
  float* out     = (float*)d_out;

  const size_t kb    = (size_t)NB * TK * DH;            // elements per tensor
  const size_t kvB   = kb * 2 * 2;                      // Kb + Vt (bf16, 16.8 MB)
  const size_t permB = (size_t)NB * TQ * sizeof(int);   // 131 KB
  const size_t baseB = kvB + permB;

  // pick deepest split the workspace allows: nchs=2 (4 chunks of 8 tiles),
  // nchs=1 (2 chunks of 16), nchs=0 (sorted, unsplit)
  int nchs = -1;
  size_t pLB = 0;
  for (int s = 2; s >= 0; --s) {
    const size_t nch = (size_t)1 << s;
    const size_t plb = (size_t)NB * QB * nch * 64 * sizeof(float);
    const size_t pob = (size_t)NB * QB * nch * 64 * DH * sizeof(float);
    const size_t need = (s > 0) ? (baseB + plb + pob) : baseB;
    if (ws_size >= need) { nchs = s; pLB = plb; break; }
  }

  if (nchs >= 0) {
    unsigned short* Kb = (unsigned short*)d_ws;
    unsigned short* Vt = Kb + kb;
    int*   perm = (int*)((char*)d_ws + kvB);
    float* pL   = (nchs > 0) ? (float*)((char*)d_ws + baseB) : nullptr;
    float* pO   = (nchs > 0) ? (float*)((char*)d_ws + baseB + pLB) : nullptr;
    sort_kernel<<<dim3(NB), 256, 0, stream>>>(vl, perm);
    prep_kernel<<<dim3(KT, NB), 256, 0, stream>>>(K, V, Kb, Vt);
    attn_ws<<<dim3(QB << nchs, NB), 256, 0, stream>>>(Q, Kb, Vt, vl, perm,
                                                      pO, pL, out, nchs);
    if (nchs > 0)
      combine_kernel<<<dim3(QB, NB), 256, 0, stream>>>(pO, pL, perm, vl, out, nchs);
  } else if (ws_size >= kvB) {
    // unsorted unsplit (previous behavior)
    unsigned short* Kb = (unsigned short*)d_ws;
    unsigned short* Vt = Kb + kb;
    prep_kernel<<<dim3(KT, NB), 256, 0, stream>>>(K, V, Kb, Vt);
    attn_ws<<<dim3(QB, NB), 256, 0, stream>>>(Q, Kb, Vt, vl, nullptr,
                                              nullptr, nullptr, out, 0);
  } else {
    attn_fb<<<dim3(QB, NB), 256, 0, stream>>>(Q, K, V, vl, out);
  }
}

// Round 4
// 179.303 us; speedup vs baseline: 3.2376x; 1.1572x over previous
//
#include <hip/hip_runtime.h>
#include <stdint.h>
#include <math.h>

#define NB 16
#define TQ 2048
#define TK 2048
#define DH 128
#define KT (TK / 64)   // 32 k-tiles
#define QB (TQ / 64)   // 32 q-blocks per batch

// split-K chunking (fixed for the persistent path)
#define CT   8         // tiles per chunk
#define CTL  3         // log2(CT)
#define NCH  4         // KT / CT
#define NJOBS (NB * QB * NCH)   // 2048 job slots
#define PBLK 512       // persistent blocks = 2 per CU (r0-proven residency)

// padded LDS strides (shorts)
#define QK_STR 136   // 128 + 8
#define VT_STR 72    // 64 + 8
#define P_STR  72

typedef __attribute__((ext_vector_type(8))) short bf16x8;
typedef __attribute__((ext_vector_type(4))) float f32x4;
typedef __attribute__((ext_vector_type(8))) unsigned short u16x8;

__device__ __forceinline__ unsigned short f2b(float f) {
  union { float f; uint32_t u; } v; v.f = f;
  uint32_t u = v.u;
  return (unsigned short)((u + 0x7fffu + ((u >> 16) & 1u)) >> 16);
}

__device__ __forceinline__ u16x8 cvt8(const float* p) {
  const f32x4 a = *(const f32x4*)p;
  const f32x4 b = *(const f32x4*)(p + 4);
  u16x8 o;
#pragma unroll
  for (int j = 0; j < 4; ++j) { o[j] = f2b(a[j]); o[4 + j] = f2b(b[j]); }
  return o;
}

// effective length: clamp to [0,TK]; vl==0 spans all of TK (uniform softmax)
__device__ __forceinline__ int eff_len(const int* vlen, bool is64, int idx) {
  int v = is64 ? vlen[2 * idx] : vlen[idx];
  v = (v < 0) ? 0 : ((v > TK) ? TK : v);
  return (v == 0) ? TK : v;
}

// ---- per-batch counting sort of q-rows by effective length (DESCENDING).
// Rank q0 of any block holds the block max -> nt from one perm+vlen load.
// Block 0 also zeroes the job-ticket counter (stream order guards attn).
__global__ __launch_bounds__(256) void sort_kernel(const int* __restrict__ vlen,
                                                   int* __restrict__ perm,
                                                   int* __restrict__ tick) {
  __shared__ int cnt_[TK + 1];
  __shared__ int base_[TK + 1];
  __shared__ int psum[256];
  const int b = blockIdx.x;
  const int t = threadIdx.x;

  if (tick && b == 0 && t == 0) tick[0] = 0;

  int hw = 0;
#pragma unroll
  for (int i = 0; i < 8; ++i) hw |= vlen[2 * i + 1];
  const bool is64 = (hw == 0);

  for (int i = t; i <= TK; i += 256) cnt_[i] = 0;
  __syncthreads();

  int eff[8];
#pragma unroll
  for (int j = 0; j < 8; ++j) {
    const int q = j * 256 + t;
    eff[j] = eff_len(vlen, is64, b * TQ + q);
    atomicAdd(&cnt_[eff[j]], 1);
  }
  __syncthreads();

  // descending prefix: thread t owns positions p = 8t..8t+7, bin e = TK - p
  int loc[8]; int s = 0;
#pragma unroll
  for (int j = 0; j < 8; ++j) { loc[j] = cnt_[TK - (t * 8 + j)]; s += loc[j]; }
  psum[t] = s;
  __syncthreads();
  if (t == 0) {
    int acc = 0;
    for (int i = 0; i < 256; ++i) { const int x = psum[i]; psum[i] = acc; acc += x; }
  }
  __syncthreads();
  int run = psum[t];
#pragma unroll
  for (int j = 0; j < 8; ++j) { base_[TK - (t * 8 + j)] = run; run += loc[j]; }
  __syncthreads();
#pragma unroll
  for (int j = 0; j < 8; ++j) {
    const int rank = atomicAdd(&base_[eff[j]], 1);
    perm[b * TQ + rank] = j * 256 + t;
  }
}

// ---- prep: K f32 -> bf16 row-major; V f32 -> bf16 TILED-transposed:
// Vt[((b*KT + kt)*DH + d)*64 + k]  (16 KB contiguous per k-tile, coalesced writes)
__global__ __launch_bounds__(256) void prep_kernel(const float* __restrict__ K,
                                                   const float* __restrict__ V,
                                                   unsigned short* __restrict__ Kb,
                                                   unsigned short* __restrict__ Vt) {
  __shared__ alignas(16) unsigned short tile[64][136];
  const int t = threadIdx.x;
  const int b = blockIdx.y;
  const int kt = blockIdx.x;
  const int k0 = kt * 64;

  const float* Ks = K + ((size_t)b * TK + k0) * DH;
  unsigned short* Kd = Kb + ((size_t)b * TK + k0) * DH;
#pragma unroll
  for (int i = 0; i < 4; ++i) {
    const int row = i * 16 + (t >> 4);
    const int c0 = (t & 15) * 8;
    *(u16x8*)(Kd + (size_t)row * DH + c0) = cvt8(Ks + (size_t)row * DH + c0);
  }
  const float* Vs = V + ((size_t)b * TK + k0) * DH;
#pragma unroll
  for (int i = 0; i < 4; ++i) {
    const int row = i * 16 + (t >> 4);
    const int c0 = (t & 15) * 8;
    *(u16x8*)(&tile[row][c0]) = cvt8(Vs + (size_t)row * DH + c0);
  }
  __syncthreads();
  {
    const int d = t >> 1;          // 0..127
    const int half = t & 1;        // k-half
    alignas(16) unsigned short tmp[32];
#pragma unroll
    for (int j = 0; j < 32; ++j) tmp[j] = tile[half * 32 + j][d];
    unsigned short* dst = Vt + ((size_t)(b * KT + kt) * DH + d) * 64 + half * 32;
#pragma unroll
    for (int j = 0; j < 4; ++j)
      *(u16x8*)(dst + j * 8) = *(const u16x8*)(&tmp[j * 8]);
  }
}

// ---- persistent fused flash attention, fixed-max softmax.
// p = exp2(s*scale - 32); shift-invariance -> O = (P V)/sum(P) exact, and
// partials across k-chunks are addable -> exact split-K.
// EXACTLY PBLK=512 blocks (2/CU, r0-proven residency) stay resident and pull
// (c,j,b) jobs from a global atomic ticket, big jobs (c=0) first. Each job is
// <= CT=8 k-tiles of one sorted q-block. nact==1 jobs write out directly;
// others write partials; combine_kernel (separate launch = the cross-XCD
// fence, NOT per-block threadfence -- round-2 lesson) finishes.
__global__ __launch_bounds__(256) void attn_pers(const float* __restrict__ Q,
                                                 const unsigned short* __restrict__ Kp,
                                                 const unsigned short* __restrict__ Vp,
                                                 const int* __restrict__ vlen,
                                                 const int* __restrict__ perm,
                                                 float* __restrict__ pO,
                                                 float* __restrict__ pL,
                                                 float* __restrict__ out,
                                                 int* __restrict__ tick) {
  __shared__ alignas(16) char smem[53248];
  __shared__ int s_job;
  unsigned short* sQ = (unsigned short*)smem;
  unsigned short* sK = (unsigned short*)(smem + 17408);
  unsigned short* sV = (unsigned short*)(smem + 34816);

  const int tid  = threadIdx.x;
  const int w    = tid >> 6;
  const int lane = tid & 63;
  const int quad = lane >> 4;
  const int l15  = lane & 15;
  const int krow = tid >> 4;
  const int kch  = tid & 15;

  // valid_lens: detect int32 vs int64 (little-endian: high dwords all zero)
  int hw = 0;
#pragma unroll
  for (int i = 0; i < 8; ++i) hw |= vlen[2 * i + 1];
  const bool is64 = (hw == 0);

  const float kScaleL2 = 0.08838834764831845f * 1.4426950408889634f; // 1/sqrt(128)*log2(e)
  const float kBias    = -32.0f;
  const float kKill    = -1.0e7f;

  for (;;) {
    __syncthreads();               // LDS + s_job reuse guard between jobs
    if (tid == 0) s_job = atomicAdd(tick, 1);
    __syncthreads();
    const int job = s_job;
    if (job >= NJOBS) return;      // uniform exit

    // decode: c-major (all size-8 chunks first), then j, then batch
    const int cchunk = job >> 9;          // 0..3
    const int jq     = (job >> 4) & 31;   // 0..31
    const int b      = job & 15;          // 0..15
    const int q0 = jq * 64;
    const int qw = q0 + w * 16;

    // sorted descending: rank q0 / qw hold the block / wave maxes
    const int bvl = eff_len(vlen, is64, b * TQ + perm[b * TQ + q0]);
    const int wvl = eff_len(vlen, is64, b * TQ + perm[b * TQ + qw]);
    const int nt = (bvl + 63) >> 6;
    const int t0 = cchunk * CT;
    const int t1 = (nt < t0 + CT) ? nt : (t0 + CT);
    if (t0 >= t1) continue;               // inactive job: cheap skip
    const int nact = (nt + CT - 1) >> CTL;

    // per-row lengths / scales / source rows
    int vlr[4]; float scl[4]; int qidx[4];
#pragma unroll
    for (int r = 0; r < 4; ++r) {
      const int rank = qw + quad * 4 + r;
      const int qrow = perm[b * TQ + rank];
      qidx[r] = qrow;
      const int idx = b * TQ + qrow;
      int v = is64 ? vlen[2 * idx] : vlen[idx];
      v = (v < 0) ? 0 : ((v > TK) ? TK : v);
      scl[r] = (v == 0) ? 0.0f : kScaleL2;
      vlr[r] = (v == 0) ? TK : v;
    }

    // Q staging (rows gathered through perm; each row is 512B contiguous)
#pragma unroll
    for (int i = 0; i < 4; ++i) {
      const int row = i * 16 + (tid >> 4);
      const int qi = perm[b * TQ + q0 + row];
      const int c0 = (tid & 15) * 8;
      *(u16x8*)(sQ + row * QK_STR + c0) = cvt8(Q + ((size_t)b * TQ + qi) * DH + c0);
    }
    __syncthreads();

    // Q fragments (A-layout: m=l15, k=quad*8+j per K=32 chunk kc)
    bf16x8 qa[4];
    {
      const unsigned short* qrow = sQ + (w * 16 + l15) * QK_STR;
#pragma unroll
      for (int kc = 0; kc < 4; ++kc)
        qa[kc] = *(const bf16x8*)(qrow + (kc * 4 + quad) * 8);
    }
    unsigned short* sP = (unsigned short*)smem + w * (16 * P_STR);  // aliases sQ

    f32x4 Of[8] = {};
    float l_r[4] = {0.f, 0.f, 0.f, 0.f};

    const unsigned short* Kbase = Kp + (size_t)b * TK * DH;
    const unsigned short* Vbase = Vp + (size_t)(b * KT) * DH * 64;

    u16x8 kreg[4], vreg[4];
    // prefetch tile t0
    {
      const unsigned short* Ksrc = Kbase + (size_t)t0 * 64 * DH;
#pragma unroll
      for (int i = 0; i < 4; ++i)
        kreg[i] = *(const u16x8*)(Ksrc + (size_t)(i * 16 + krow) * DH + kch * 8);
      const unsigned short* Vsrc = Vbase + (size_t)t0 * (DH * 64);
#pragma unroll
      for (int i = 0; i < 4; ++i)
        vreg[i] = *(const u16x8*)(Vsrc + (i * 256 + tid) * 8);
    }

    for (int t = t0; t < t1; ++t) {
      // store prefetched tile into LDS
#pragma unroll
      for (int i = 0; i < 4; ++i)
        *(u16x8*)(sK + (i * 16 + krow) * QK_STR + kch * 8) = kreg[i];
#pragma unroll
      for (int i = 0; i < 4; ++i) {
        const int chunk = i * 256 + tid;
        *(u16x8*)(sV + (chunk >> 3) * VT_STR + (chunk & 7) * 8) = vreg[i];
      }
      __syncthreads();

      // issue next tile's global loads early
      if (t + 1 < t1) {
        const unsigned short* Ksrc = Kbase + (size_t)(t + 1) * 64 * DH;
#pragma unroll
        for (int i = 0; i < 4; ++i)
          kreg[i] = *(const u16x8*)(Ksrc + (size_t)(i * 16 + krow) * DH + kch * 8);
        const unsigned short* Vsrc = Vbase + (size_t)(t + 1) * (DH * 64);
#pragma unroll
        for (int i = 0; i < 4; ++i)
          vreg[i] = *(const u16x8*)(Vsrc + (i * 256 + tid) * 8);
      }

      const int k0 = t * 64;
      if (k0 < wvl) {   // wave-uniform skip of fully-masked tiles
        // S = Q K^T  (C: col=l15=kpos, row=quad*4+reg=q-row)
        f32x4 sc[4] = {};
#pragma unroll
        for (int ct = 0; ct < 4; ++ct) {
          const unsigned short* kr = sK + (ct * 16 + l15) * QK_STR;
#pragma unroll
          for (int kc = 0; kc < 4; ++kc) {
            const bf16x8 kf = *(const bf16x8*)(kr + (kc * 4 + quad) * 8);
            sc[ct] = __builtin_amdgcn_mfma_f32_16x16x32_bf16(qa[kc], kf, sc[ct], 0, 0, 0);
          }
        }

        // fixed-max masked softmax numerator, accumulate row sums per-lane
        unsigned short pb[4][4];
#pragma unroll
        for (int ct = 0; ct < 4; ++ct) {
          const int kpos = k0 + ct * 16 + l15;
#pragma unroll
          for (int r = 0; r < 4; ++r) {
            const float s = (kpos < vlr[r]) ? fmaf(sc[ct][r], scl[r], kBias) : kKill;
            const float p = exp2f(s);
            l_r[r] += p;
            pb[ct][r] = f2b(p);
          }
        }

        // P (C-layout) -> per-wave LDS; same-wave DS ops in order
#pragma unroll
        for (int ct = 0; ct < 4; ++ct)
#pragma unroll
          for (int r = 0; r < 4; ++r)
            sP[(quad * 4 + r) * P_STR + ct * 16 + l15] = pb[ct][r];
        __asm__ __volatile__("" ::: "memory");

        bf16x8 pa[2];
        {
          const unsigned short* pr = sP + l15 * P_STR;
#pragma unroll
          for (int ch = 0; ch < 2; ++ch)
            pa[ch] = *(const bf16x8*)(pr + (ch * 4 + quad) * 8);
        }

        // O += P V  (B-frag: n=l15=d-col, k=quad*8+j=kpos)
#pragma unroll
        for (int dt = 0; dt < 8; ++dt) {
          const unsigned short* vr = sV + (dt * 16 + l15) * VT_STR;
#pragma unroll
          for (int ch = 0; ch < 2; ++ch) {
            const bf16x8 vf = *(const bf16x8*)(vr + (ch * 4 + quad) * 8);
            Of[dt] = __builtin_amdgcn_mfma_f32_16x16x32_bf16(pa[ch], vf, Of[dt], 0, 0, 0);
          }
        }
      }
      __syncthreads();
    }

    // cross-lane row-sum reduction (over the 16 l15 lanes per quad)
#pragma unroll
    for (int off = 1; off <= 8; off <<= 1)
#pragma unroll
      for (int r = 0; r < 4; ++r)
        l_r[r] += __shfl_xor(l_r[r], off, 64);

    if (nact == 1) {
      // single active chunk: normalize + scatter directly
#pragma unroll
      for (int r = 0; r < 4; ++r) {
        const float inv = 1.0f / l_r[r];
        float* orow = out + ((size_t)b * TQ + qidx[r]) * DH;
#pragma unroll
        for (int dt = 0; dt < 8; ++dt)
          orow[dt * 16 + l15] = Of[dt][r] * inv;
      }
      continue;
    }

    // split path: write partial numerator + denominator (rank-local layout)
    const int slot = (b * QB + jq) * NCH + cchunk;
    float* po = pO + (size_t)slot * (64 * DH);
    float* pl = pL + (size_t)slot * 64;
#pragma unroll
    for (int r = 0; r < 4; ++r) {
      const int row = w * 16 + quad * 4 + r;
#pragma unroll
      for (int dt = 0; dt < 8; ++dt)
        po[(size_t)row * DH + dt * 16 + l15] = Of[dt][r];
    }
    if (l15 == 0) {
#pragma unroll
      for (int r = 0; r < 4; ++r)
        pl[w * 16 + quad * 4 + r] = l_r[r];
    }
  }
}

// ---- combine: O = (Σ_c P_c) / (Σ_c l_c), scatter rank -> q via perm.
// Only q-blocks with nact >= 2 have pending partials; others exit fast.
__global__ __launch_bounds__(256) void combine_kernel(const float* __restrict__ pO,
                                                      const float* __restrict__ pL,
                                                      const int* __restrict__ perm,
                                                      const int* __restrict__ vlen,
                                                      float* __restrict__ out) {
  const int b = blockIdx.y;
  const int j = blockIdx.x;
  const int t = threadIdx.x;

  int hw = 0;
#pragma unroll
  for (int i = 0; i < 8; ++i) hw |= vlen[2 * i + 1];
  const bool is64 = (hw == 0);

  const int bvl = eff_len(vlen, is64, b * TQ + perm[b * TQ + j * 64]);
  const int nt = (bvl + 63) >> 6;
  const int nact = (nt + CT - 1) >> CTL;
  if (nact <= 1) return;   // handled by attn_pers direct path

  const int qboff = (b * QB + j) * NCH;
#pragma unroll
  for (int i = 0; i < 8; ++i) {
    const int u = i * 256 + t;        // 2048 f32x4 units = 64 rows * 32
    const int r = u >> 5;             // rank-local row
    const int d4 = (u & 31) * 4;
    float lsum = 0.0f;
    f32x4 acc = {0.f, 0.f, 0.f, 0.f};
    for (int c = 0; c < nact; ++c) {
      lsum += pL[(size_t)(qboff + c) * 64 + r];
      acc += *(const f32x4*)(pO + ((size_t)(qboff + c) * 64 + r) * DH + d4);
    }
    const float inv = 1.0f / lsum;
    const int qi = perm[b * TQ + j * 64 + r];
    *(f32x4*)(out + ((size_t)b * TQ + qi) * DH + d4) = acc * inv;
  }
}

// ---- fallback (no workspace): f32 inputs, in-kernel cvt, strided V B-frags ----
__global__ __launch_bounds__(256) void attn_fb(const float* __restrict__ Q,
                                               const float* __restrict__ Kp,
                                               const float* __restrict__ Vp,
                                               const int* __restrict__ vlen,
                                               float* __restrict__ out) {
  __shared__ alignas(16) char smem[53248];
  __shared__ int s_bvl[4];
  unsigned short* sQ = (unsigned short*)smem;
  unsigned short* sK = (unsigned short*)(smem + 17408);
  unsigned short* sV = (unsigned short*)(smem + 34816);

  const int tid  = threadIdx.x;
  const int w    = tid >> 6;
  const int lane = tid & 63;
  const int quad = lane >> 4;
  const int l15  = lane & 15;
  const int b    = blockIdx.y;
  const int q0   = blockIdx.x * 64;

  const float* Qb = Q + ((size_t)b * TQ + q0) * DH;
#pragma unroll
  for (int i = 0; i < 4; ++i) {
    const int row = i * 16 + (tid >> 4);
    const int c0 = (tid & 15) * 8;
    *(u16x8*)(sQ + row * QK_STR + c0) = cvt8(Qb + (size_t)row * DH + c0);
  }

  int hw = 0;
#pragma unroll
  for (int i = 0; i < 8; ++i) hw |= vlen[2 * i + 1];
  const bool is64 = (hw == 0);

  const float kScaleL2 = 0.08838834764831845f * 1.4426950408889634f;
  const float kBias    = -32.0f;
  const float kKill    = -1.0e7f;

  const int qw = q0 + w * 16;
  int vlr[4];
  float scl[4];
#pragma unroll
  for (int r = 0; r < 4; ++r) {
    const int idx = b * TQ + qw + quad * 4 + r;
    int v = is64 ? vlen[2 * idx] : vlen[idx];
    v = (v < 0) ? 0 : ((v > TK) ? TK : v);
    scl[r] = (v == 0) ? 0.0f : kScaleL2;
    vlr[r] = (v == 0) ? TK : v;
  }
  int wvl = 0;
#pragma unroll
  for (int r = 0; r < 4; ++r) wvl = max(wvl, vlr[r]);
  wvl = max(wvl, __shfl_xor(wvl, 16, 64));
  wvl = max(wvl, __shfl_xor(wvl, 32, 64));
  if (lane == 0) s_bvl[w] = wvl;
  __syncthreads();
  const int bvl = max(max(s_bvl[0], s_bvl[1]), max(s_bvl[2], s_bvl[3]));
  const int nt = (bvl + 63) >> 6;

  bf16x8 qa[4];
  {
    const unsigned short* qrow = sQ + (w * 16 + l15) * QK_STR;
#pragma unroll
    for (int kc = 0; kc < 4; ++kc)
      qa[kc] = *(const bf16x8*)(qrow + (kc * 4 + quad) * 8);
  }
  unsigned short* sP = (unsigned short*)smem + w * (16 * P_STR);

  f32x4 Of[8] = {};
  float l_r[4] = {0.f, 0.f, 0.f, 0.f};

  const float* Kb = Kp + (size_t)b * TK * DH;
  const float* Vb = Vp + (size_t)b * TK * DH;

  for (int t = 0; t < nt; ++t) {
    const int k0 = t * 64;
    __syncthreads();
#pragma unroll
    for (int i = 0; i < 4; ++i) {
      const int row = i * 16 + (tid >> 4);
      const int c0 = (tid & 15) * 8;
      *(u16x8*)(sK + row * QK_STR + c0) = cvt8(Kb + (size_t)(k0 + row) * DH + c0);
    }
#pragma unroll
    for (int i = 0; i < 4; ++i) {
      const int row = i * 16 + (tid >> 4);
      const int c0 = (tid & 15) * 8;
      *(u16x8*)(sV + row * QK_STR + c0) = cvt8(Vb + (size_t)(k0 + row) * DH + c0);
    }
    __syncthreads();
    if (k0 >= wvl) continue;

    f32x4 sc[4] = {};
#pragma unroll
    for (int ct = 0; ct < 4; ++ct) {
      const unsigned short* kr = sK + (ct * 16 + l15) * QK_STR;
#pragma unroll
      for (int kc = 0; kc < 4; ++kc) {
        const bf16x8 kf = *(const bf16x8*)(kr + (kc * 4 + quad) * 8);
        sc[ct] = __builtin_amdgcn_mfma_f32_16x16x32_bf16(qa[kc], kf, sc[ct], 0, 0, 0);
      }
    }
    unsigned short pb[4][4];
#pragma unroll
    for (int ct = 0; ct < 4; ++ct) {
      const int kpos = k0 + ct * 16 + l15;
#pragma unroll
      for (int r = 0; r < 4; ++r) {
        const float s = (kpos < vlr[r]) ? fmaf(sc[ct][r], scl[r], kBias) : kKill;
        const float p = exp2f(s);
        l_r[r] += p;
        pb[ct][r] = f2b(p);
      }
    }
#pragma unroll
    for (int ct = 0; ct < 4; ++ct)
#pragma unroll
      for (int r = 0; r < 4; ++r)
        sP[(quad * 4 + r) * P_STR + ct * 16 + l15] = pb[ct][r];
    __asm__ __volatile__("" ::: "memory");
    bf16x8 pa[2];
    {
      const unsigned short* pr = sP + l15 * P_STR;
#pragma unroll
      for (int ch = 0; ch < 2; ++ch)
        pa[ch] = *(const bf16x8*)(pr + (ch * 4 + quad) * 8);
    }
#pragma unroll
    for (int dt = 0; dt < 8; ++dt) {
      const int col = dt * 16 + l15;
#pragma unroll
      for (int ch = 0; ch < 2; ++ch) {
        bf16x8 vf;
#pragma unroll
        for (int j = 0; j < 8; ++j) {
          const int k = ch * 32 + quad * 8 + j;
          vf[j] = ((const short*)sV)[k * QK_STR + col];
        }
        Of[dt] = __builtin_amdgcn_mfma_f32_16x16x32_bf16(pa[ch], vf, Of[dt], 0, 0, 0);
      }
    }
  }

#pragma unroll
  for (int off = 1; off <= 8; off <<= 1)
#pragma unroll
    for (int r = 0; r < 4; ++r)
      l_r[r] += __shfl_xor(l_r[r], off, 64);

#pragma unroll
  for (int r = 0; r < 4; ++r) {
    const float inv = 1.0f / l_r[r];
    const int q = qw + quad * 4 + r;
    float* orow = out + ((size_t)b * TQ + q) * DH;
#pragma unroll
    for (int dt = 0; dt < 8; ++dt)
      orow[dt * 16 + l15] = Of[dt][r] * inv;
  }
}

extern "C" void kernel_launch(void* const* d_in, const int* in_sizes, int n_in,
                              void* d_out, int out_size, void* d_ws, size_t ws_size,
                              hipStream_t stream) {
  const float* Q = (const float*)d_in[0];
  const float* K = (const float*)d_in[1];
  const float* V = (const float*)d_in[2];
  const int* vl  = (const int*)d_in[3];
  float* out     = (float*)d_out;

  const size_t kb    = (size_t)NB * TK * DH;            // elements per tensor
  const size_t kvB   = kb * 2 * 2;                      // Kb + Vt (bf16, 16.8 MB)
  const size_t permB = (size_t)NB * TQ * sizeof(int);   // 131 KB
  const size_t tickB = 256;                             // job ticket (padded)
  const size_t pLB   = (size_t)NB * QB * NCH * 64 * sizeof(float);        // 524 KB
  const size_t pOB   = (size_t)NB * QB * NCH * 64 * DH * sizeof(float);   // 67 MB

  if (ws_size >= kvB + permB + tickB + pLB + pOB) {
    // tier 1: sorted + persistent dynamic split-K + combine
    unsigned short* Kb = (unsigned short*)d_ws;
    unsigned short* Vt = Kb + kb;
    int*   perm = (int*)((char*)d_ws + kvB);
    int*   tick = (int*)((char*)d_ws + kvB + permB);
    float* pL   = (float*)((char*)d_ws + kvB + permB + tickB);
    float* pO   = (float*)((char*)d_ws + kvB + permB + tickB + pLB);
    sort_kernel<<<dim3(NB), 256, 0, stream>>>(vl, perm, tick);
    prep_kernel<<<dim3(KT, NB), 256, 0, stream>>>(K, V, Kb, Vt);
    attn_pers<<<dim3(PBLK), 256, 0, stream>>>(Q, Kb, Vt, vl, perm, pO, pL, out, tick);
    combine_kernel<<<dim3(QB, NB), 256, 0, stream>>>(pO, pL, perm, vl, out);
  } else {
    attn_fb<<<dim3(QB, NB), 256, 0, stream>>>(Q, K, V, vl, out);
  }
}

// Round 5
// 176.578 us; speedup vs baseline: 3.2875x; 1.0154x over previous
//
#include <hip/hip_runtime.h>
#include <stdint.h>
#include <math.h>

#define NB 16
#define TQ 2048
#define TK 2048
#define DH 128
#define KT (TK / 64)   // 32 k-tiles
#define QB (TQ / 64)   // 32 q-blocks per batch

// split-K chunking (fixed for the persistent path)
#define CT   8         // tiles per chunk
#define CTL  3         // log2(CT)
#define NCH  4         // KT / CT
#define NJOBS (NB * QB * NCH)   // 2048 job slots
// persistent blocks: 3 per CU. LDS 53760B alloc x3 = 161280 <= 163840 OK;
// VGPR 104 -> 4 waves/SIMD possible, 3 blocks need only 3. (r4 ran 2/CU at
// C=1.30 effective; time tracked 8448 tiles x 2.9us / (256*C) exactly.)
#define PBLK 768

// padded LDS strides (shorts)
#define QK_STR 136   // 128 + 8
#define VT_STR 72    // 64 + 8
#define P_STR  72

typedef __attribute__((ext_vector_type(8))) short bf16x8;
typedef __attribute__((ext_vector_type(4))) float f32x4;
typedef __attribute__((ext_vector_type(8))) unsigned short u16x8;

__device__ __forceinline__ unsigned short f2b(float f) {
  union { float f; uint32_t u; } v; v.f = f;
  uint32_t u = v.u;
  return (unsigned short)((u + 0x7fffu + ((u >> 16) & 1u)) >> 16);
}

__device__ __forceinline__ u16x8 cvt8(const float* p) {
  const f32x4 a = *(const f32x4*)p;
  const f32x4 b = *(const f32x4*)(p + 4);
  u16x8 o;
#pragma unroll
  for (int j = 0; j < 4; ++j) { o[j] = f2b(a[j]); o[4 + j] = f2b(b[j]); }
  return o;
}

// effective length: clamp to [0,TK]; vl==0 spans all of TK (uniform softmax)
__device__ __forceinline__ int eff_len(const int* vlen, bool is64, int idx) {
  int v = is64 ? vlen[2 * idx] : vlen[idx];
  v = (v < 0) ? 0 : ((v > TK) ? TK : v);
  return (v == 0) ? TK : v;
}

// ---- fused prep + sort (one launch instead of two).
// blockIdx.x <  KT : K f32 -> bf16 row-major; V f32 -> bf16 TILED-transposed
//                    Vt[((b*KT + kt)*DH + d)*64 + k]
// blockIdx.x == KT : per-batch counting sort of q-rows by effective length
//                    (DESCENDING) -> perm; block (KT, 0) zeroes the ticket.
__global__ __launch_bounds__(256) void prep_sort(const float* __restrict__ K,
                                                 const float* __restrict__ V,
                                                 unsigned short* __restrict__ Kb,
                                                 unsigned short* __restrict__ Vt,
                                                 const int* __restrict__ vlen,
                                                 int* __restrict__ perm,
                                                 int* __restrict__ tick) {
  __shared__ alignas(16) char sm[17424];   // max(prep 17408, sort 17416)
  const int t = threadIdx.x;
  const int b = blockIdx.y;

  if (blockIdx.x == KT) {
    // ---------------- sort path ----------------
    int* cnt_  = (int*)sm;           // TK+1
    int* base_ = cnt_ + (TK + 1);    // TK+1
    int* psum  = base_ + (TK + 1);   // 256

    if (b == 0 && t == 0) tick[0] = 0;

    int hw = 0;
#pragma unroll
    for (int i = 0; i < 8; ++i) hw |= vlen[2 * i + 1];
    const bool is64 = (hw == 0);

    for (int i = t; i <= TK; i += 256) cnt_[i] = 0;
    __syncthreads();

    int eff[8];
#pragma unroll
    for (int j = 0; j < 8; ++j) {
      const int q = j * 256 + t;
      eff[j] = eff_len(vlen, is64, b * TQ + q);
      atomicAdd(&cnt_[eff[j]], 1);
    }
    __syncthreads();

    // descending prefix: thread t owns positions p = 8t..8t+7, bin e = TK - p
    int loc[8]; int s = 0;
#pragma unroll
    for (int j = 0; j < 8; ++j) { loc[j] = cnt_[TK - (t * 8 + j)]; s += loc[j]; }
    psum[t] = s;
    __syncthreads();
    if (t == 0) {
      int acc = 0;
      for (int i = 0; i < 256; ++i) { const int x = psum[i]; psum[i] = acc; acc += x; }
    }
    __syncthreads();
    int run = psum[t];
#pragma unroll
    for (int j = 0; j < 8; ++j) { base_[TK - (t * 8 + j)] = run; run += loc[j]; }
    __syncthreads();
#pragma unroll
    for (int j = 0; j < 8; ++j) {
      const int rank = atomicAdd(&base_[eff[j]], 1);
      perm[b * TQ + rank] = j * 256 + t;
    }
    return;
  }

  // ---------------- prep path ----------------
  unsigned short (*tile)[136] = (unsigned short (*)[136])sm;
  const int kt = blockIdx.x;
  const int k0 = kt * 64;

  const float* Ks = K + ((size_t)b * TK + k0) * DH;
  unsigned short* Kd = Kb + ((size_t)b * TK + k0) * DH;
#pragma unroll
  for (int i = 0; i < 4; ++i) {
    const int row = i * 16 + (t >> 4);
    const int c0 = (t & 15) * 8;
    *(u16x8*)(Kd + (size_t)row * DH + c0) = cvt8(Ks + (size_t)row * DH + c0);
  }
  const float* Vs = V + ((size_t)b * TK + k0) * DH;
#pragma unroll
  for (int i = 0; i < 4; ++i) {
    const int row = i * 16 + (t >> 4);
    const int c0 = (t & 15) * 8;
    *(u16x8*)(&tile[row][c0]) = cvt8(Vs + (size_t)row * DH + c0);
  }
  __syncthreads();
  {
    const int d = t >> 1;          // 0..127
    const int half = t & 1;        // k-half
    alignas(16) unsigned short tmp[32];
#pragma unroll
    for (int j = 0; j < 32; ++j) tmp[j] = tile[half * 32 + j][d];
    unsigned short* dst = Vt + ((size_t)(b * KT + kt) * DH + d) * 64 + half * 32;
#pragma unroll
    for (int j = 0; j < 4; ++j)
      *(u16x8*)(dst + j * 8) = *(const u16x8*)(&tmp[j * 8]);
  }
}

// ---- persistent fused flash attention, fixed-max softmax.
// p = exp2(s*scale - 32); shift-invariance -> O = (P V)/sum(P) exact, and
// partials across k-chunks are addable -> exact split-K.
// EXACTLY PBLK=768 blocks (3/CU) stay resident and pull (c,j,b) jobs from a
// global atomic ticket, big jobs (c=0) first. Each job is <= CT=8 k-tiles of
// one sorted q-block. nact==1 jobs write out directly; others write partials;
// combine_kernel (separate launch = the cross-XCD fence, NOT per-block
// threadfence -- round-2 lesson) finishes.
__global__ __launch_bounds__(256) void attn_pers(const float* __restrict__ Q,
                                                 const unsigned short* __restrict__ Kp,
                                                 const unsigned short* __restrict__ Vp,
                                                 const int* __restrict__ vlen,
                                                 const int* __restrict__ perm,
                                                 float* __restrict__ pO,
                                                 float* __restrict__ pL,
                                                 float* __restrict__ out,
                                                 int* __restrict__ tick) {
  __shared__ alignas(16) char smem[53248];
  __shared__ int s_job;
  unsigned short* sQ = (unsigned short*)smem;
  unsigned short* sK = (unsigned short*)(smem + 17408);
  unsigned short* sV = (unsigned short*)(smem + 34816);

  const int tid  = threadIdx.x;
  const int w    = tid >> 6;
  const int lane = tid & 63;
  const int quad = lane >> 4;
  const int l15  = lane & 15;
  const int krow = tid >> 4;
  const int kch  = tid & 15;

  // valid_lens: detect int32 vs int64 (little-endian: high dwords all zero)
  int hw = 0;
#pragma unroll
  for (int i = 0; i < 8; ++i) hw |= vlen[2 * i + 1];
  const bool is64 = (hw == 0);

  const float kScaleL2 = 0.08838834764831845f * 1.4426950408889634f; // 1/sqrt(128)*log2(e)
  const float kBias    = -32.0f;
  const float kKill    = -1.0e7f;

  for (;;) {
    __syncthreads();               // LDS + s_job reuse guard between jobs
    if (tid == 0) s_job = atomicAdd(tick, 1);
    __syncthreads();
    const int job = s_job;
    if (job >= NJOBS) return;      // uniform exit

    // decode: c-major (all size-8 chunks first), then j, then batch
    const int cchunk = job >> 9;          // 0..3
    const int jq     = (job >> 4) & 31;   // 0..31
    const int b      = job & 15;          // 0..15
    const int q0 = jq * 64;
    const int qw = q0 + w * 16;

    // sorted descending: rank q0 / qw hold the block / wave maxes
    const int bvl = eff_len(vlen, is64, b * TQ + perm[b * TQ + q0]);
    const int wvl = eff_len(vlen, is64, b * TQ + perm[b * TQ + qw]);
    const int nt = (bvl + 63) >> 6;
    const int t0 = cchunk * CT;
    const int t1 = (nt < t0 + CT) ? nt : (t0 + CT);
    if (t0 >= t1) continue;               // inactive job: cheap skip
    const int nact = (nt + CT - 1) >> CTL;

    // per-row lengths / scales / source rows
    int vlr[4]; float scl[4]; int qidx[4];
#pragma unroll
    for (int r = 0; r < 4; ++r) {
      const int rank = qw + quad * 4 + r;
      const int qrow = perm[b * TQ + rank];
      qidx[r] = qrow;
      const int idx = b * TQ + qrow;
      int v = is64 ? vlen[2 * idx] : vlen[idx];
      v = (v < 0) ? 0 : ((v > TK) ? TK : v);
      scl[r] = (v == 0) ? 0.0f : kScaleL2;
      vlr[r] = (v == 0) ? TK : v;
    }

    // Q staging (rows gathered through perm; each row is 512B contiguous)
#pragma unroll
    for (int i = 0; i < 4; ++i) {
      const int row = i * 16 + (tid >> 4);
      const int qi = perm[b * TQ + q0 + row];
      const int c0 = (tid & 15) * 8;
      *(u16x8*)(sQ + row * QK_STR + c0) = cvt8(Q + ((size_t)b * TQ + qi) * DH + c0);
    }
    __syncthreads();

    // Q fragments (A-layout: m=l15, k=quad*8+j per K=32 chunk kc)
    bf16x8 qa[4];
    {
      const unsigned short* qrow = sQ + (w * 16 + l15) * QK_STR;
#pragma unroll
      for (int kc = 0; kc < 4; ++kc)
        qa[kc] = *(const bf16x8*)(qrow + (kc * 4 + quad) * 8);
    }
    unsigned short* sP = (unsigned short*)smem + w * (16 * P_STR);  // aliases sQ

    f32x4 Of[8] = {};
    float l_r[4] = {0.f, 0.f, 0.f, 0.f};

    const unsigned short* Kbase = Kp + (size_t)b * TK * DH;
    const unsigned short* Vbase = Vp + (size_t)(b * KT) * DH * 64;

    u16x8 kreg[4], vreg[4];
    // prefetch tile t0
    {
      const unsigned short* Ksrc = Kbase + (size_t)t0 * 64 * DH;
#pragma unroll
      for (int i = 0; i < 4; ++i)
        kreg[i] = *(const u16x8*)(Ksrc + (size_t)(i * 16 + krow) * DH + kch * 8);
      const unsigned short* Vsrc = Vbase + (size_t)t0 * (DH * 64);
#pragma unroll
      for (int i = 0; i < 4; ++i)
        vreg[i] = *(const u16x8*)(Vsrc + (i * 256 + tid) * 8);
    }

    for (int t = t0; t < t1; ++t) {
      // store prefetched tile into LDS
#pragma unroll
      for (int i = 0; i < 4; ++i)
        *(u16x8*)(sK + (i * 16 + krow) * QK_STR + kch * 8) = kreg[i];
#pragma unroll
      for (int i = 0; i < 4; ++i) {
        const int chunk = i * 256 + tid;
        *(u16x8*)(sV + (chunk >> 3) * VT_STR + (chunk & 7) * 8) = vreg[i];
      }
      __syncthreads();

      // issue next tile's global loads early
      if (t + 1 < t1) {
        const unsigned short* Ksrc = Kbase + (size_t)(t + 1) * 64 * DH;
#pragma unroll
        for (int i = 0; i < 4; ++i)
          kreg[i] = *(const u16x8*)(Ksrc + (size_t)(i * 16 + krow) * DH + kch * 8);
        const unsigned short* Vsrc = Vbase + (size_t)(t + 1) * (DH * 64);
#pragma unroll
        for (int i = 0; i < 4; ++i)
          vreg[i] = *(const u16x8*)(Vsrc + (i * 256 + tid) * 8);
      }

      const int k0 = t * 64;
      if (k0 < wvl) {   // wave-uniform skip of fully-masked tiles
        // S = Q K^T  (C: col=l15=kpos, row=quad*4+reg=q-row)
        f32x4 sc[4] = {};
#pragma unroll
        for (int ct = 0; ct < 4; ++ct) {
          const unsigned short* kr = sK + (ct * 16 + l15) * QK_STR;
#pragma unroll
          for (int kc = 0; kc < 4; ++kc) {
            const bf16x8 kf = *(const bf16x8*)(kr + (kc * 4 + quad) * 8);
            sc[ct] = __builtin_amdgcn_mfma_f32_16x16x32_bf16(qa[kc], kf, sc[ct], 0, 0, 0);
          }
        }

        // fixed-max masked softmax numerator, accumulate row sums per-lane
        unsigned short pb[4][4];
#pragma unroll
        for (int ct = 0; ct < 4; ++ct) {
          const int kpos = k0 + ct * 16 + l15;
#pragma unroll
          for (int r = 0; r < 4; ++r) {
            const float s = (kpos < vlr[r]) ? fmaf(sc[ct][r], scl[r], kBias) : kKill;
            const float p = exp2f(s);
            l_r[r] += p;
            pb[ct][r] = f2b(p);
          }
        }

        // P (C-layout) -> per-wave LDS; same-wave DS ops in order
#pragma unroll
        for (int ct = 0; ct < 4; ++ct)
#pragma unroll
          for (int r = 0; r < 4; ++r)
            sP[(quad * 4 + r) * P_STR + ct * 16 + l15] = pb[ct][r];
        __asm__ __volatile__("" ::: "memory");

        bf16x8 pa[2];
        {
          const unsigned short* pr = sP + l15 * P_STR;
#pragma unroll
          for (int ch = 0; ch < 2; ++ch)
            pa[ch] = *(const bf16x8*)(pr + (ch * 4 + quad) * 8);
        }

        // O += P V  (B-frag: n=l15=d-col, k=quad*8+j=kpos)
#pragma unroll
        for (int dt = 0; dt < 8; ++dt) {
          const unsigned short* vr = sV + (dt * 16 + l15) * VT_STR;
#pragma unroll
          for (int ch = 0; ch < 2; ++ch) {
            const bf16x8 vf = *(const bf16x8*)(vr + (ch * 4 + quad) * 8);
            Of[dt] = __builtin_amdgcn_mfma_f32_16x16x32_bf16(pa[ch], vf, Of[dt], 0, 0, 0);
          }
        }
      }
      __syncthreads();
    }

    // cross-lane row-sum reduction (over the 16 l15 lanes per quad)
#pragma unroll
    for (int off = 1; off <= 8; off <<= 1)
#pragma unroll
      for (int r = 0; r < 4; ++r)
        l_r[r] += __shfl_xor(l_r[r], off, 64);

    if (nact == 1) {
      // single active chunk: normalize + scatter directly
#pragma unroll
      for (int r = 0; r < 4; ++r) {
        const float inv = 1.0f / l_r[r];
        float* orow = out + ((size_t)b * TQ + qidx[r]) * DH;
#pragma unroll
        for (int dt = 0; dt < 8; ++dt)
          orow[dt * 16 + l15] = Of[dt][r] * inv;
      }
      continue;
    }

    // split path: write partial numerator + denominator (rank-local layout)
    const int slot = (b * QB + jq) * NCH + cchunk;
    float* po = pO + (size_t)slot * (64 * DH);
    float* pl = pL + (size_t)slot * 64;
#pragma unroll
    for (int r = 0; r < 4; ++r) {
      const int row = w * 16 + quad * 4 + r;
#pragma unroll
      for (int dt = 0; dt < 8; ++dt)
        po[(size_t)row * DH + dt * 16 + l15] = Of[dt][r];
    }
    if (l15 == 0) {
#pragma unroll
      for (int r = 0; r < 4; ++r)
        pl[w * 16 + quad * 4 + r] = l_r[r];
    }
  }
}

// ---- combine: O = (Σ_c P_c) / (Σ_c l_c), scatter rank -> q via perm.
// Only q-blocks with nact >= 2 have pending partials; others exit fast.
__global__ __launch_bounds__(256) void combine_kernel(const float* __restrict__ pO,
                                                      const float* __restrict__ pL,
                                                      const int* __restrict__ perm,
                                                      const int* __restrict__ vlen,
                                                      float* __restrict__ out) {
  const int b = blockIdx.y;
  const int j = blockIdx.x;
  const int t = threadIdx.x;

  int hw = 0;
#pragma unroll
  for (int i = 0; i < 8; ++i) hw |= vlen[2 * i + 1];
  const bool is64 = (hw == 0);

  const int bvl = eff_len(vlen, is64, b * TQ + perm[b * TQ + j * 64]);
  const int nt = (bvl + 63) >> 6;
  const int nact = (nt + CT - 1) >> CTL;
  if (nact <= 1) return;   // handled by attn_pers direct path

  const int qboff = (b * QB + j) * NCH;
#pragma unroll
  for (int i = 0; i < 8; ++i) {
    const int u = i * 256 + t;        // 2048 f32x4 units = 64 rows * 32
    const int r = u >> 5;             // rank-local row
    const int d4 = (u & 31) * 4;
    float lsum = 0.0f;
    f32x4 acc = {0.f, 0.f, 0.f, 0.f};
    for (int c = 0; c < nact; ++c) {
      lsum += pL[(size_t)(qboff + c) * 64 + r];
      acc += *(const f32x4*)(pO + ((size_t)(qboff + c) * 64 + r) * DH + d4);
    }
    const float inv = 1.0f / lsum;
    const int qi = perm[b * TQ + j * 64 + r];
    *(f32x4*)(out + ((size_t)b * TQ + qi) * DH + d4) = acc * inv;
  }
}

// ---- fallback (no workspace): f32 inputs, in-kernel cvt, strided V B-frags ----
__global__ __launch_bounds__(256) void attn_fb(const float* __restrict__ Q,
                                               const float* __restrict__ Kp,
                                               const float* __restrict__ Vp,
                                               const int* __restrict__ vlen,
                                               float* __restrict__ out) {
  __shared__ alignas(16) char smem[53248];
  __shared__ int s_bvl[4];
  unsigned short* sQ = (unsigned short*)smem;
  unsigned short* sK = (unsigned short*)(smem + 17408);
  unsigned short* sV = (unsigned short*)(smem + 34816);

  const int tid  = threadIdx.x;
  const int w    = tid >> 6;
  const int lane = tid & 63;
  const int quad = lane >> 4;
  const int l15  = lane & 15;
  const int b    = blockIdx.y;
  const int q0   = blockIdx.x * 64;

  const float* Qb = Q + ((size_t)b * TQ + q0) * DH;
#pragma unroll
  for (int i = 0; i < 4; ++i) {
    const int row = i * 16 + (tid >> 4);
    const int c0 = (tid & 15) * 8;
    *(u16x8*)(sQ + row * QK_STR + c0) = cvt8(Qb + (size_t)row * DH + c0);
  }

  int hw = 0;
#pragma unroll
  for (int i = 0; i < 8; ++i) hw |= vlen[2 * i + 1];
  const bool is64 = (hw == 0);

  const float kScaleL2 = 0.08838834764831845f * 1.4426950408889634f;
  const float kBias    = -32.0f;
  const float kKill    = -1.0e7f;

  const int qw = q0 + w * 16;
  int vlr[4];
  float scl[4];
#pragma unroll
  for (int r = 0; r < 4; ++r) {
    const int idx = b * TQ + qw + quad * 4 + r;
    int v = is64 ? vlen[2 * idx] : vlen[idx];
    v = (v < 0) ? 0 : ((v > TK) ? TK : v);
    scl[r] = (v == 0) ? 0.0f : kScaleL2;
    vlr[r] = (v == 0) ? TK : v;
  }
  int wvl = 0;
#pragma unroll
  for (int r = 0; r < 4; ++r) wvl = max(wvl, vlr[r]);
  wvl = max(wvl, __shfl_xor(wvl, 16, 64));
  wvl = max(wvl, __shfl_xor(wvl, 32, 64));
  if (lane == 0) s_bvl[w] = wvl;
  __syncthreads();
  const int bvl = max(max(s_bvl[0], s_bvl[1]), max(s_bvl[2], s_bvl[3]));
  const int nt = (bvl + 63) >> 6;

  bf16x8 qa[4];
  {
    const unsigned short* qrow = sQ + (w * 16 + l15) * QK_STR;
#pragma unroll
    for (int kc = 0; kc < 4; ++kc)
      qa[kc] = *(const bf16x8*)(qrow + (kc * 4 + quad) * 8);
  }
  unsigned short* sP = (unsigned short*)smem + w * (16 * P_STR);

  f32x4 Of[8] = {};
  float l_r[4] = {0.f, 0.f, 0.f, 0.f};

  const float* Kb = Kp + (size_t)b * TK * DH;
  const float* Vb = Vp + (size_t)b * TK * DH;

  for (int t = 0; t < nt; ++t) {
    const int k0 = t * 64;
    __syncthreads();
#pragma unroll
    for (int i = 0; i < 4; ++i) {
      const int row = i * 16 + (tid >> 4);
      const int c0 = (tid & 15) * 8;
      *(u16x8*)(sK + row * QK_STR + c0) = cvt8(Kb + (size_t)(k0 + row) * DH + c0);
    }
#pragma unroll
    for (int i = 0; i < 4; ++i) {
      const int row = i * 16 + (tid >> 4);
      const int c0 = (tid & 15) * 8;
      *(u16x8*)(sV + row * QK_STR + c0) = cvt8(Vb + (size_t)(k0 + row) * DH + c0);
    }
    __syncthreads();
    if (k0 >= wvl) continue;

    f32x4 sc[4] = {};
#pragma unroll
    for (int ct = 0; ct < 4; ++ct) {
      const unsigned short* kr = sK + (ct * 16 + l15) * QK_STR;
#pragma unroll
      for (int kc = 0; kc < 4; ++kc) {
        const bf16x8 kf = *(const bf16x8*)(kr + (kc * 4 + quad) * 8);
        sc[ct] = __builtin_amdgcn_mfma_f32_16x16x32_bf16(qa[kc], kf, sc[ct], 0, 0, 0);
      }
    }
    unsigned short pb[4][4];
#pragma unroll
    for (int ct = 0; ct < 4; ++ct) {
      const int kpos = k0 + ct * 16 + l15;
#pragma unroll
      for (int r = 0; r < 4; ++r) {
        const float s = (kpos < vlr[r]) ? fmaf(sc[ct][r], scl[r], kBias) : kKill;
        const float p = exp2f(s);
        l_r[r] += p;
        pb[ct][r] = f2b(p);
      }
    }
#pragma unroll
    for (int ct = 0; ct < 4; ++ct)
#pragma unroll
      for (int r = 0; r < 4; ++r)
        sP[(quad * 4 + r) * P_STR + ct * 16 + l15] = pb[ct][r];
    __asm__ __volatile__("" ::: "memory");
    bf16x8 pa[2];
    {
      const unsigned short* pr = sP + l15 * P_STR;
#pragma unroll
      for (int ch = 0; ch < 2; ++ch)
        pa[ch] = *(const bf16x8*)(pr + (ch * 4 + quad) * 8);
    }
#pragma unroll
    for (int dt = 0; dt < 8; ++dt) {
      const int col = dt * 16 + l15;
#pragma unroll
      for (int ch = 0; ch < 2; ++ch) {
        bf16x8 vf;
#pragma unroll
        for (int j = 0; j < 8; ++j) {
          const int k = ch * 32 + quad * 8 + j;
          vf[j] = ((const short*)sV)[k * QK_STR + col];
        }
        Of[dt] = __builtin_amdgcn_mfma_f32_16x16x32_bf16(pa[ch], vf, Of[dt], 0, 0, 0);
      }
    }
  }

#pragma unroll
  for (int off = 1; off <= 8; off <<= 1)
#pragma unroll
    for (int r = 0; r < 4; ++r)
      l_r[r] += __shfl_xor(l_r[r], off, 64);

#pragma unroll
  for (int r = 0; r < 4; ++r) {
    const float inv = 1.0f / l_r[r];
    const int q = qw + quad * 4 + r;
    float* orow = out + ((size_t)b * TQ + q) * DH;
#pragma unroll
    for (int dt = 0; dt < 8; ++dt)
      orow[dt * 16 + l15] = Of[dt][r] * inv;
  }
}

extern "C" void kernel_launch(void* const* d_in, const int* in_sizes, int n_in,
                              void* d_out, int out_size, void* d_ws, size_t ws_size,
                              hipStream_t stream) {
  const float* Q = (const float*)d_in[0];
  const float* K = (const float*)d_in[1];
  const float* V = (const float*)d_in[2];
  const int* vl  = (const int*)d_in[3];
  float* out     = (float*)d_out;

  const size_t kb    = (size_t)NB * TK * DH;            // elements per tensor
  const size_t kvB   = kb * 2 * 2;                      // Kb + Vt (bf16, 16.8 MB)
  const size_t permB = (size_t)NB * TQ * sizeof(int);   // 131 KB
  const size_t tickB = 256;                             // job ticket (padded)
  const size_t pLB   = (size_t)NB * QB * NCH * 64 * sizeof(float);        // 524 KB
  const size_t pOB   = (size_t)NB * QB * NCH * 64 * DH * sizeof(float);   // 67 MB

  if (ws_size >= kvB + permB + tickB + pLB + pOB) {
    // tier 1: fused prep+sort, persistent dynamic split-K, combine
    unsigned short* Kb = (unsigned short*)d_ws;
    unsigned short* Vt = Kb + kb;
    int*   perm = (int*)((char*)d_ws + kvB);
    int*   tick = (int*)((char*)d_ws + kvB + permB);
    float* pL   = (float*)((char*)d_ws + kvB + permB + tickB);
    float* pO   = (float*)((char*)d_ws + kvB + permB + tickB + pLB);
    prep_sort<<<dim3(KT + 1, NB), 256, 0, stream>>>(K, V, Kb, Vt, vl, perm, tick);
    attn_pers<<<dim3(PBLK), 256, 0, stream>>>(Q, Kb, Vt, vl, perm, pO, pL, out, tick);
    combine_kernel<<<dim3(QB, NB), 256, 0, stream>>>(pO, pL, perm, vl, out);
  } else {
    attn_fb<<<dim3(QB, NB), 256, 0, stream>>>(Q, K, V, vl, out);
  }
}